// Round 11
// baseline (10373.882 us; speedup 1.0000x reference)
//
#include <hip/hip_runtime.h>
#include <hip/hip_bf16.h>
#include <stdint.h>

#define BATCH 8
#define NPTS  16384
#define DIMF  64
#define SPTS  1024
#define NSAMP 32
#define MTOT  (BATCH*SPTS*NSAMP)   // 262144
#define CELLS 512                  // 8x8x8 spatial grid for FPS pruning

__device__ __forceinline__ float bfu_lo(uint32_t u){ return __uint_as_float(u<<16); }
__device__ __forceinline__ float bfu_hi(uint32_t u){ return __uint_as_float(u & 0xffff0000u); }
__device__ __forceinline__ uint16_t f2bf(float f){
  __hip_bfloat16 h = __float2bfloat16(f);
  uint16_t u; __builtin_memcpy(&u, &h, 2); return u;
}

__device__ __forceinline__ unsigned long long shfl_xor_u64(unsigned long long v, int off){
  unsigned lo = (unsigned)v, hi = (unsigned)(v>>32);
  lo = __shfl_xor(lo, off); hi = __shfl_xor(hi, off);
  return ((unsigned long long)hi<<32) | lo;
}

// ---------------- prep: transpose points (B,64,N)->(B,N,64) ----------------
__global__ __launch_bounds__(256) void transpose_kernel(const float* __restrict__ pts,
                                                        float* __restrict__ ptsT){
  __shared__ float tile[32][33];
  int b = blockIdx.z;
  int n0 = blockIdx.x*32, c0 = blockIdx.y*32;
  int tx = threadIdx.x & 31, ty = threadIdx.x >> 5;
  const float* src = pts + (size_t)b*DIMF*NPTS;
  float* dst = ptsT + (size_t)b*NPTS*DIMF;
#pragma unroll
  for (int j=0;j<4;j++)
    tile[ty+8*j][tx] = src[(size_t)(c0+ty+8*j)*NPTS + n0 + tx];
  __syncthreads();
#pragma unroll
  for (int j=0;j<4;j++)
    dst[(size_t)(n0+ty+8*j)*DIMF + c0 + tx] = tile[tx][ty+8*j];
}

__device__ __forceinline__ int cell_of(float x, float y, float z){
  int ix=(int)(x*8.0f); ix = ix<0?0:(ix>7?7:ix);
  int iy=(int)(y*8.0f); iy = iy<0?0:(iy>7?7:iy);
  int iz=(int)(z*8.0f); iz = iz<0?0:(iz>7?7:iz);
  return (ix<<6)|(iy<<3)|iz;
}

// ---------------- FPS: bucket-pruned, SINGLE-WAVE main loop ----------------
// 8 waves do histogram/scan/scatter; then waves 1-7 retire and wave 0 runs all
// 1023 iterations wave-synchronously: no barriers, no cross-wave state. Cell
// state (packed max, winner coords, ranges) lives in wave-0 registers: lane
// owns cells c = j*64+lane, j=0..7 (statically unrolled). dst in LDS; sorted
// float4 points L2-resident in global scratch.
// Distance chain + first-max tie semantics bit-identical to verified kernels;
// pruning margin validated in R9/R10.
__global__ __launch_bounds__(512) void fps_kernel(const float* __restrict__ xyz,
                                                  float* __restrict__ out0,
                                                  float4* __restrict__ sortg){
  int b = blockIdx.x;
  const float* X = xyz + (size_t)b*3*NPTS;
  float4* sp = sortg + (size_t)b*NPTS;
  int t = threadIdx.x, lane = t & 63, w = t >> 6;   // 8 waves

  __shared__ float dst_s[NPTS];          // 64 KB
  __shared__ int   hist[CELLS];
  __shared__ int   cursor[CELLS];
  __shared__ int   cstart[CELLS+1];
  __shared__ int   wsum[8];

  // --- histogram ---
  if (t < CELLS) hist[t] = 0;
  __syncthreads();
#pragma unroll
  for (int k=0;k<32;k++){
    int n = t + (k<<9);
    atomicAdd(&hist[cell_of(X[n],X[NPTS+n],X[2*NPTS+n])],1);
  }
  __syncthreads();
  // --- exclusive scan over 512 ---
  {
    int v = hist[t], inc = v;
#pragma unroll
    for (int off=1; off<64; off<<=1){ int u=__shfl_up(inc,off); if(lane>=off) inc+=u; }
    if (lane==63) wsum[w] = inc;
    __syncthreads();
    if (t==0){ int acc=0; for(int i=0;i<8;i++){int x=wsum[i]; wsum[i]=acc; acc+=x;} }
    __syncthreads();
    int ex = inc - v + wsum[w];
    cstart[t]=ex; cursor[t]=ex;
    if (t==0) cstart[CELLS]=NPTS;
  }
  __syncthreads();
  // --- scatter sorted copy (x,y,z,orig) ---
#pragma unroll
  for (int k=0;k<32;k++){
    int n = t + (k<<9);
    float x=X[n], y=X[NPTS+n], z=X[2*NPTS+n];
    int c = cell_of(x,y,z);
    int pos = atomicAdd(&cursor[c],1);
    sp[pos] = make_float4(x,y,z,__int_as_float(n));
  }
  __syncthreads();
  if (w != 0) return;        // single-wave main loop; no barriers follow

  // ---- wave 0 state: lane owns cells c=j*64+lane ----
  int st[8], en[8];
#pragma unroll
  for (int j=0;j<8;j++){ int c=j*64+lane; st[j]=cstart[c]; en[j]=cstart[c+1]; }
  float loy = (float)(lane>>3)*0.125f, loz = (float)(lane&7)*0.125f;
  unsigned long long rpk[8];
  float rx[8], ry[8], rz[8];

  float cx=X[0], cy=X[NPTS], cz=X[2*NPTS];   // first centroid = point 0
  float* o = out0 + (size_t)b*3*SPTS;
  if (lane==0){ o[0]=cx; o[SPTS]=cy; o[2*SPTS]=cz; }

  // ---- s=0: per-lane build of all cells (dst starts at 1e10 -> d wins min) ----
#pragma unroll
  for (int j=0;j<8;j++){
    unsigned long long bp=0ull; float bx=0.f,by=0.f,bz=0.f;
    for (int pos=st[j]; pos<en[j]; ++pos){
      float4 pq = sp[pos];
      float ddx=__fsub_rn(pq.x,cx), ddy=__fsub_rn(pq.y,cy), ddz=__fsub_rn(pq.z,cz);
      float d = __fadd_rn(__fadd_rn(__fmul_rn(ddx,ddx),__fmul_rn(ddy,ddy)),
                          __fmul_rn(ddz,ddz));
      dst_s[pos] = d;
      int orig = __float_as_int(pq.w);
      unsigned long long pk =
        ((unsigned long long)__float_as_uint(d)<<32) | (unsigned)(16383-orig);
      if (pk > bp){ bp=pk; bx=pq.x; by=pq.y; bz=pq.z; }
    }
    rpk[j]=bp; rx[j]=bx; ry[j]=by; rz[j]=bz;
  }

  for (int s=1; s<SPTS; s++){
    // ---- global argmax over cell maxima (register state) ----
    unsigned long long bm=rpk[0]; float bx=rx[0], by=ry[0], bz=rz[0];
#pragma unroll
    for (int j=1;j<8;j++){
      if (rpk[j] > bm){ bm=rpk[j]; bx=rx[j]; by=ry[j]; bz=rz[j]; }
    }
    unsigned long long rm=bm;
#pragma unroll
    for (int off=1; off<64; off<<=1){
      unsigned long long om = shfl_xor_u64(rm, off);
      rm = (om>rm)? om : rm;
    }
    int wl = (int)__builtin_ctzll(__ballot(bm==rm));
    cx = __shfl(bx, wl); cy = __shfl(by, wl); cz = __shfl(bz, wl);
    if (lane==0){ o[s]=cx; o[SPTS+s]=cy; o[2*SPTS+s]=cz; }
    if (s==SPTS-1) break;
    // ---- dirty test + whole-wave update of dirty cells ----
    float dyy = fmaxf(fmaxf(loy-cy, cy-(loy+0.125f)),0.f);
    float dzz = fmaxf(fmaxf(loz-cz, cz-(loz+0.125f)),0.f);
    float dyz2 = dyy*dyy + dzz*dzz;
#pragma unroll
    for (int j=0;j<8;j++){
      float lox = (float)j*0.125f;
      float dxx = fmaxf(fmaxf(lox-cx, cx-(lox+0.125f)),0.f);
      float lb  = dxx*dxx + dyz2;
      float cmv = __uint_as_float((unsigned)(rpk[j]>>32));
      bool dd = (st[j]<en[j]) && ((lb*(1.0f-4e-6f)-4e-6f) < cmv);
      unsigned long long mj = __ballot(dd);
      while (mj){
        int l = (int)__builtin_ctzll(mj); mj &= mj-1;
        int cs = __shfl(st[j], l), ce = __shfl(en[j], l);
        unsigned long long bp=0ull; float px=0.f,py=0.f,pz=0.f;
        for (int base=cs; base<ce; base+=64){
          int pos = base+lane;
          if (pos < ce){
            float4 pq = sp[pos];
            float od = dst_s[pos];
            float ddx=__fsub_rn(pq.x,cx), ddy=__fsub_rn(pq.y,cy), ddz=__fsub_rn(pq.z,cz);
            float d = __fadd_rn(__fadd_rn(__fmul_rn(ddx,ddx),__fmul_rn(ddy,ddy)),
                                __fmul_rn(ddz,ddz));
            d = fminf(od, d);
            dst_s[pos] = d;
            int orig = __float_as_int(pq.w);
            unsigned long long pk =
              ((unsigned long long)__float_as_uint(d)<<32) | (unsigned)(16383-orig);
            if (pk > bp){ bp=pk; px=pq.x; py=pq.y; pz=pq.z; }
          }
        }
        unsigned long long rp=bp;
#pragma unroll
        for (int off=1; off<64; off<<=1){
          unsigned long long op = shfl_xor_u64(rp, off);
          rp = (op>rp)? op : rp;
        }
        int wl2 = (int)__builtin_ctzll(__ballot(bp==rp));
        float gx=__shfl(px,wl2), gy=__shfl(py,wl2), gz=__shfl(pz,wl2);
        if (lane==l){ rpk[j]=rp; rx[j]=gx; ry[j]=gy; rz[j]=gz; }
      }
    }
  }
}

// ---------------- ball query: XLA-CPU f32 replication ----------------
// A (query norm), B (point norm): plain sequential ((x^2+y^2)+z^2)  [XLA reduce, no FMA]
// C (dot): Eigen gemm FMA chain fma(z*nz, fma(y*ny, x*nx))          [einsum -> Eigen]
// sqr = (A+B) - 2*C  (x2 exact, fuse-independent)
__global__ __launch_bounds__(256) void ball_kernel(const float* __restrict__ xyz,
                                                   const float* __restrict__ newxyz,
                                                   int* __restrict__ idxo){
  int b  = blockIdx.x >> 5;
  int sc = blockIdx.x & 31;           // 32 s per block
  const float* X  = xyz + (size_t)b*3*NPTS;
  int t = threadIdx.x, lane = t & 63, w = t >> 6;
  __shared__ float lx[512], ly[512], lz[512], ls[512];
  __shared__ int done;
  if (t==0) done = 0;
  const float rsq = 0.01f;
  float nx[8], ny[8], nz[8], sn[8];
  int cnt[8], first[8];
  int sbase = sc*32 + w*8;
#pragma unroll
  for (int q=0;q<8;q++){
    int s = sbase + q;
    nx[q] = newxyz[(size_t)b*3*SPTS + s];
    ny[q] = newxyz[(size_t)b*3*SPTS + SPTS + s];
    nz[q] = newxyz[(size_t)b*3*SPTS + 2*SPTS + s];
    sn[q] = __fadd_rn(__fadd_rn(__fmul_rn(nx[q],nx[q]),__fmul_rn(ny[q],ny[q])),
                      __fmul_rn(nz[q],nz[q]));
    cnt[q]=0; first[q]=0;
  }
  __syncthreads();
  for (int T=0;T<32;T++){
    {
      float ax = X[T*512 + t], ay = X[NPTS + T*512 + t], az = X[2*NPTS + T*512 + t];
      lx[t]=ax; ly[t]=ay; lz[t]=az;
      ls[t] = __fadd_rn(__fadd_rn(__fmul_rn(ax,ax),__fmul_rn(ay,ay)),__fmul_rn(az,az));
      float bx = X[T*512 + t + 256], by = X[NPTS + T*512 + t + 256], bz = X[2*NPTS + T*512 + t + 256];
      lx[t+256]=bx; ly[t+256]=by; lz[t+256]=bz;
      ls[t+256] = __fadd_rn(__fadd_rn(__fmul_rn(bx,bx),__fmul_rn(by,by)),__fmul_rn(bz,bz));
    }
    __syncthreads();
#pragma unroll
    for (int q=0;q<8;q++){
      if (cnt[q] >= NSAMP) continue;
      int s = sbase + q;
      int* op = idxo + ((size_t)(b*SPTS + s))*NSAMP;
      for (int c=0;c<8;c++){
        int li = c*64 + lane;
        float dot = fmaf(nz[q], lz[li], fmaf(ny[q], ly[li], __fmul_rn(nx[q], lx[li])));
        float sq  = __fsub_rn(__fadd_rn(sn[q], ls[li]), __fmul_rn(2.0f, dot));
        bool in = (sq <= rsq);
        unsigned long long m = __ballot(in);
        if (cnt[q]==0 && m) first[q] = T*512 + c*64 + (int)__builtin_ctzll(m);
        if (in){
          int slot = cnt[q] + (int)__popcll(m & ((1ull<<lane)-1ull));
          if (slot < NSAMP) op[slot] = T*512 + li;
        }
        cnt[q] += (int)__popcll(m);
        if (cnt[q] >= NSAMP){ if (lane==0) atomicAdd(&done,1); break; }
      }
    }
    __syncthreads();
    if (done >= 32) break;   // uniform across the block
  }
#pragma unroll
  for (int q=0;q<8;q++){
    if (cnt[q] < NSAMP){
      int s = sbase + q;
      int* op = idxo + ((size_t)(b*SPTS + s))*NSAMP;
      if (lane >= cnt[q] && lane < NSAMP) op[lane] = first[q];
    }
  }
}

// ---------------- GEMM1: fused gather (xyz diff + pts) x w1 -> y1 (bf16) ----------------
__global__ __launch_bounds__(256) void gemm1_kernel(const float* __restrict__ xyz,
                                                    const float* __restrict__ ptsT,
                                                    const int* __restrict__ idx,
                                                    const float* __restrict__ newxyz,
                                                    const float* __restrict__ w1,
                                                    const float* __restrict__ b1,
                                                    uint16_t* __restrict__ y1){
  __shared__ float As[128*69];
  __shared__ float Ws[67*64];
  __shared__ float bias[64];
  __shared__ int   ndx[128];
  __shared__ float nxs[4][3];
  int t = threadIdx.x;
  int g0 = blockIdx.x*128;
  if (t < 128) ndx[t] = idx[g0 + t];
  if (t < 12){
    int grp = t/3, c = t%3;
    int bs = (g0>>5) + grp; int b = bs>>10, s = bs & 1023;
    nxs[grp][c] = newxyz[(size_t)b*3*SPTS + c*SPTS + s];
  }
  if (t < 64) bias[t] = b1[t];
  for (int e=t; e<67*64; e+=256){ int k=e>>6, c=e&63; Ws[k*64+c] = w1[c*67+k]; }
  __syncthreads();
  {
    int r = t>>1, h = t&1;
    int n = ndx[r];
    int bs = (g0>>5) + (r>>5); int b = bs>>10;
    const float* pr = ptsT + ((size_t)(b*NPTS + n))*64 + h*32;
    float* ar = As + r*69;
    if (h==0){
      int grp = r>>5;
      ar[0] = __fsub_rn(xyz[(size_t)b*3*NPTS + n],          nxs[grp][0]);
      ar[1] = __fsub_rn(xyz[(size_t)b*3*NPTS + NPTS + n],   nxs[grp][1]);
      ar[2] = __fsub_rn(xyz[(size_t)b*3*NPTS + 2*NPTS + n], nxs[grp][2]);
    }
    float* ap = ar + 3 + h*32;
#pragma unroll
    for (int j=0;j<8;j++){
      float4 v = *(const float4*)(pr + j*4);
      ap[j*4+0]=v.x; ap[j*4+1]=v.y; ap[j*4+2]=v.z; ap[j*4+3]=v.w;
    }
  }
  __syncthreads();
  int rg = t>>3, cg = t&7;
  float acc[4][8];
#pragma unroll
  for (int i=0;i<4;i++)
#pragma unroll
    for (int j=0;j<8;j++) acc[i][j]=0.f;
  for (int k=0;k<67;k++){
    float a0 = As[(rg*4+0)*69+k];
    float a1 = As[(rg*4+1)*69+k];
    float a2 = As[(rg*4+2)*69+k];
    float a3 = As[(rg*4+3)*69+k];
    const float* wr = Ws + k*64 + cg*8;
    float4 w0 = *(const float4*)wr;
    float4 w1v = *(const float4*)(wr+4);
    float wj[8] = {w0.x,w0.y,w0.z,w0.w,w1v.x,w1v.y,w1v.z,w1v.w};
#pragma unroll
    for (int j=0;j<8;j++){
      acc[0][j] = fmaf(a0, wj[j], acc[0][j]);
      acc[1][j] = fmaf(a1, wj[j], acc[1][j]);
      acc[2][j] = fmaf(a2, wj[j], acc[2][j]);
      acc[3][j] = fmaf(a3, wj[j], acc[3][j]);
    }
  }
#pragma unroll
  for (int i=0;i<4;i++){
    int gr = g0 + rg*4 + i;
    uint16_t* yr = y1 + (size_t)gr*64 + cg*8;
    uint4 vv;
    uint32_t u[4];
#pragma unroll
    for (int j=0;j<4;j++){
      float v0 = acc[i][2*j]   + bias[cg*8+2*j];
      float v1 = acc[i][2*j+1] + bias[cg*8+2*j+1];
      u[j] = (uint32_t)f2bf(v0) | ((uint32_t)f2bf(v1)<<16);
    }
    vv.x=u[0]; vv.y=u[1]; vv.z=u[2]; vv.w=u[3];
    *(uint4*)yr = vv;
  }
}

// ---------------- GEMM2: relu(bn(y1)) x w2 -> y2 (bf16), K=64 ----------------
__global__ __launch_bounds__(256) void gemm2_kernel(const uint16_t* __restrict__ yin,
                                                    const float* __restrict__ w2,
                                                    const float* __restrict__ b2,
                                                    const float* __restrict__ scale,
                                                    const float* __restrict__ shift,
                                                    uint16_t* __restrict__ yout){
  __shared__ float As[128*65];
  __shared__ float Ws[64*64];
  __shared__ float bias[64], sc[64], sh[64];
  int t = threadIdx.x;
  int g0 = blockIdx.x*128;
  if (t < 64){ bias[t]=b2[t]; sc[t]=scale[t]; sh[t]=shift[t]; }
  for (int e=t; e<64*64; e+=256){ int k=e>>6, c=e&63; Ws[k*64+c] = w2[c*64+k]; }
  __syncthreads();
  {
    int r = t>>1, h = t&1;
    const uint4* yv = (const uint4*)(yin + (size_t)(g0+r)*64 + h*32);
    float* ar = As + r*65 + h*32;
#pragma unroll
    for (int j=0;j<4;j++){
      uint4 u = yv[j];
      uint32_t vv[4] = {u.x,u.y,u.z,u.w};
#pragma unroll
      for (int m=0;m<4;m++){
        int c = h*32 + j*8 + m*2;
        ar[j*8+m*2]   = fmaxf(fmaf(bfu_lo(vv[m]), sc[c],   sh[c]),   0.f);
        ar[j*8+m*2+1] = fmaxf(fmaf(bfu_hi(vv[m]), sc[c+1], sh[c+1]), 0.f);
      }
    }
  }
  __syncthreads();
  int rg = t>>3, cg = t&7;
  float acc[4][8];
#pragma unroll
  for (int i=0;i<4;i++)
#pragma unroll
    for (int j=0;j<8;j++) acc[i][j]=0.f;
  for (int k=0;k<64;k++){
    float a0 = As[(rg*4+0)*65+k];
    float a1 = As[(rg*4+1)*65+k];
    float a2 = As[(rg*4+2)*65+k];
    float a3 = As[(rg*4+3)*65+k];
    const float* wr = Ws + k*64 + cg*8;
    float4 w0 = *(const float4*)wr;
    float4 w1v = *(const float4*)(wr+4);
    float wj[8] = {w0.x,w0.y,w0.z,w0.w,w1v.x,w1v.y,w1v.z,w1v.w};
#pragma unroll
    for (int j=0;j<8;j++){
      acc[0][j] = fmaf(a0, wj[j], acc[0][j]);
      acc[1][j] = fmaf(a1, wj[j], acc[1][j]);
      acc[2][j] = fmaf(a2, wj[j], acc[2][j]);
      acc[3][j] = fmaf(a3, wj[j], acc[3][j]);
    }
  }
#pragma unroll
  for (int i=0;i<4;i++){
    int gr = g0 + rg*4 + i;
    uint16_t* yr = yout + (size_t)gr*64 + cg*8;
    uint4 vv; uint32_t u[4];
#pragma unroll
    for (int j=0;j<4;j++){
      float v0 = acc[i][2*j]   + bias[cg*8+2*j];
      float v1 = acc[i][2*j+1] + bias[cg*8+2*j+1];
      u[j] = (uint32_t)f2bf(v0) | ((uint32_t)f2bf(v1)<<16);
    }
    vv.x=u[0]; vv.y=u[1]; vv.z=u[2]; vv.w=u[3];
    *(uint4*)yr = vv;
  }
}

// ---------------- GEMM3: relu(bn(y2)) x w3 -> y3 (bf16), K=64, OUT=128 ----------------
__global__ __launch_bounds__(256) void gemm3_kernel(const uint16_t* __restrict__ yin,
                                                    const float* __restrict__ w3,
                                                    const float* __restrict__ b3,
                                                    const float* __restrict__ scale,
                                                    const float* __restrict__ shift,
                                                    uint16_t* __restrict__ yout){
  __shared__ float As[64*65];
  __shared__ float Ws[64*128];
  __shared__ float bias[128], sc[64], sh[64];
  int t = threadIdx.x;
  int g0 = blockIdx.x*64;
  if (t < 128) bias[t]=b3[t];
  if (t < 64){ sc[t]=scale[t]; sh[t]=shift[t]; }
  for (int e=t; e<64*128; e+=256){ int k=e>>7, c=e&127; Ws[k*128+c] = w3[c*64+k]; }
  __syncthreads();
  {
    int r = t>>2, h = t&3;
    const uint4* yv = (const uint4*)(yin + (size_t)(g0+r)*64 + h*16);
    float* ar = As + r*65 + h*16;
#pragma unroll
    for (int j=0;j<2;j++){
      uint4 u = yv[j];
      uint32_t vv[4] = {u.x,u.y,u.z,u.w};
#pragma unroll
      for (int m=0;m<4;m++){
        int c = h*16 + j*8 + m*2;
        ar[j*8+m*2]   = fmaxf(fmaf(bfu_lo(vv[m]), sc[c],   sh[c]),   0.f);
        ar[j*8+m*2+1] = fmaxf(fmaf(bfu_hi(vv[m]), sc[c+1], sh[c+1]), 0.f);
      }
    }
  }
  __syncthreads();
  int rg = t>>4, cg = t&15;
  float acc[4][8];
#pragma unroll
  for (int i=0;i<4;i++)
#pragma unroll
    for (int j=0;j<8;j++) acc[i][j]=0.f;
  for (int k=0;k<64;k++){
    float a0 = As[(rg*4+0)*65+k];
    float a1 = As[(rg*4+1)*65+k];
    float a2 = As[(rg*4+2)*65+k];
    float a3 = As[(rg*4+3)*65+k];
    const float* wr = Ws + k*128 + cg*8;
    float4 w0 = *(const float4*)wr;
    float4 w1v = *(const float4*)(wr+4);
    float wj[8] = {w0.x,w0.y,w0.z,w0.w,w1v.x,w1v.y,w1v.z,w1v.w};
#pragma unroll
    for (int j=0;j<8;j++){
      acc[0][j] = fmaf(a0, wj[j], acc[0][j]);
      acc[1][j] = fmaf(a1, wj[j], acc[1][j]);
      acc[2][j] = fmaf(a2, wj[j], acc[2][j]);
      acc[3][j] = fmaf(a3, wj[j], acc[3][j]);
    }
  }
#pragma unroll
  for (int i=0;i<4;i++){
    int gr = g0 + rg*4 + i;
    uint16_t* yr = yout + (size_t)gr*128 + cg*8;
    uint4 vv; uint32_t u[4];
#pragma unroll
    for (int j=0;j<4;j++){
      float v0 = acc[i][2*j]   + bias[cg*8+2*j];
      float v1 = acc[i][2*j+1] + bias[cg*8+2*j+1];
      u[j] = (uint32_t)f2bf(v0) | ((uint32_t)f2bf(v1)<<16);
    }
    vv.x=u[0]; vv.y=u[1]; vv.z=u[2]; vv.w=u[3];
    *(uint4*)yr = vv;
  }
}

// ---------------- per-channel stats (sum, sumsq) ----------------
template<int C>
__global__ __launch_bounds__(256) void stats_kernel(const uint16_t* __restrict__ y,
                                                    float* __restrict__ gsum,
                                                    float* __restrict__ gsq){
  constexpr int CP  = C/2;
  constexpr int RSL = 256/CP;
  int t = threadIdx.x;
  int c0 = t % CP, rs = t / CP;
  float s0=0.f,q0=0.f,s1=0.f,q1=0.f;
#pragma unroll 4
  for (int i=0;i<512/RSL;i++){
    int r = blockIdx.x*512 + rs + i*RSL;
    uint32_t u = *(const uint32_t*)(y + (size_t)r*C + 2*c0);
    float v0 = bfu_lo(u), v1 = bfu_hi(u);
    s0 += v0; q0 += v0*v0; s1 += v1; q1 += v1*v1;
  }
  __shared__ float red[4][256];
  red[0][t]=s0; red[1][t]=q0; red[2][t]=s1; red[3][t]=q1;
  __syncthreads();
  if (t < CP){
    float a0=0,a1=0,a2=0,a3=0;
    for (int k=0;k<RSL;k++){
      a0+=red[0][k*CP+t]; a1+=red[1][k*CP+t]; a2+=red[2][k*CP+t]; a3+=red[3][k*CP+t];
    }
    atomicAdd(&gsum[2*t],   a0); atomicAdd(&gsq[2*t],   a1);
    atomicAdd(&gsum[2*t+1], a2); atomicAdd(&gsq[2*t+1], a3);
  }
}

__global__ void finalize_kernel(const float* __restrict__ gsum, const float* __restrict__ gsq,
                                const float* __restrict__ g, const float* __restrict__ be,
                                float* __restrict__ scale, float* __restrict__ shift, int C){
  int c = threadIdx.x;
  if (c >= C) return;
  double mean = (double)gsum[c] / (double)MTOT;
  double var  = (double)gsq[c] / (double)MTOT - mean*mean;
  double s    = (double)g[c] / sqrt(var + 1e-5);
  scale[c] = (float)s;
  shift[c] = (float)((double)be[c] - mean*s);
}

// ---------------- bn3 + relu + maxpool over nsample + transpose ----------------
__global__ __launch_bounds__(256) void maxpool_kernel(const uint16_t* __restrict__ y3,
                                                      const float* __restrict__ scale,
                                                      const float* __restrict__ shift,
                                                      float* __restrict__ out1){
  __shared__ float tr[16][129];
  int t = threadIdx.x;
  int b = blockIdx.x >> 6;
  int s0 = (blockIdx.x & 63) * 16;
  int ch = t & 127, sl0 = t >> 7;
  float scv = scale[ch], shv = shift[ch];
  for (int sl=sl0; sl<16; sl+=2){
    int bs = b*SPTS + s0 + sl;
    const uint16_t* yr = y3 + (size_t)bs*NSAMP*128 + ch;
    float m = 0.0f;
#pragma unroll 4
    for (int k=0;k<NSAMP;k++){
      float v = __uint_as_float(((uint32_t)yr[k*128])<<16);
      float z = fmaxf(fmaf(v, scv, shv), 0.f);
      m = fmaxf(m, z);
    }
    tr[sl][ch] = m;
  }
  __syncthreads();
  int ch2 = t >> 1, hh = t & 1;
  float vals[8];
#pragma unroll
  for (int i=0;i<8;i++) vals[i] = tr[hh*8+i][ch2];
  float* op = out1 + (size_t)b*131072 + (size_t)ch2*1024 + s0 + hh*8;
  float4 v0; v0.x=vals[0]; v0.y=vals[1]; v0.z=vals[2]; v0.w=vals[3];
  float4 v1; v1.x=vals[4]; v1.y=vals[5]; v1.z=vals[6]; v1.w=vals[7];
  *(float4*)op = v0;
  *(float4*)(op+4) = v1;
}

extern "C" void kernel_launch(void* const* d_in, const int* in_sizes, int n_in,
                              void* d_out, int out_size, void* d_ws, size_t ws_size,
                              hipStream_t stream){
  (void)in_sizes; (void)n_in; (void)out_size; (void)ws_size;
  const float* xyz = (const float*)d_in[0];
  const float* pts = (const float*)d_in[1];
  const float* w1 = (const float*)d_in[2];  const float* b1 = (const float*)d_in[3];
  const float* g1 = (const float*)d_in[4];  const float* be1 = (const float*)d_in[5];
  const float* w2 = (const float*)d_in[6];  const float* b2 = (const float*)d_in[7];
  const float* g2 = (const float*)d_in[8];  const float* be2 = (const float*)d_in[9];
  const float* w3 = (const float*)d_in[10]; const float* b3 = (const float*)d_in[11];
  const float* g3 = (const float*)d_in[12]; const float* be3 = (const float*)d_in[13];

  float* out0 = (float*)d_out;                 // (B,3,1024)
  float* out1 = out0 + BATCH*3*SPTS;           // (B,128,1024)

  char* ws = (char*)d_ws;
  float*    ptsT = (float*)(ws + 0);                       // 33,554,432 B
  int*      idx  = (int*)  (ws + 34078720);                //  1,048,576 B
  uint16_t* y1   = (uint16_t*)(ws + 35127296);             // 33,554,432 B
  uint16_t* y2   = (uint16_t*)(ws + 68681728);             // 33,554,432 B
  uint16_t* y3   = (uint16_t*)(ws + 102236160);            // 67,108,864 B
  float*    stats = (float*)(ws + 169345024);              // 1536 floats
  // FPS sorted scratch (float4 x,y,z,orig) lives inside the y1 region
  // (y1 is only written by gemm1, after fps/ball complete): 8*16384*16B = 2 MB.
  float4* sortg = (float4*)(ws + 35127296);
  float* gsum1 = stats;        float* gsq1 = stats + 128;
  float* gsum2 = stats + 256;  float* gsq2 = stats + 384;
  float* gsum3 = stats + 512;  float* gsq3 = stats + 640;
  float* scale1 = stats + 768; float* shift1 = stats + 896;
  float* scale2 = stats + 1024; float* shift2 = stats + 1152;
  float* scale3 = stats + 1280; float* shift3 = stats + 1408;

  hipMemsetAsync(stats, 0, 768*sizeof(float), stream);

  transpose_kernel<<<dim3(NPTS/32, DIMF/32, BATCH), 256, 0, stream>>>(pts, ptsT);
  fps_kernel<<<BATCH, 512, 0, stream>>>(xyz, out0, sortg);
  ball_kernel<<<BATCH*32, 256, 0, stream>>>(xyz, out0, idx);
  gemm1_kernel<<<MTOT/128, 256, 0, stream>>>(xyz, ptsT, idx, out0, w1, b1, y1);
  stats_kernel<64><<<512, 256, 0, stream>>>(y1, gsum1, gsq1);
  finalize_kernel<<<1, 128, 0, stream>>>(gsum1, gsq1, g1, be1, scale1, shift1, 64);
  gemm2_kernel<<<MTOT/128, 256, 0, stream>>>(y1, w2, b2, scale1, shift1, y2);
  stats_kernel<64><<<512, 256, 0, stream>>>(y2, gsum2, gsq2);
  finalize_kernel<<<1, 128, 0, stream>>>(gsum2, gsq2, g2, be2, scale2, shift2, 64);
  gemm3_kernel<<<MTOT/64, 256, 0, stream>>>(y2, w3, b3, scale2, shift2, y3);
  stats_kernel<128><<<512, 256, 0, stream>>>(y3, gsum3, gsq3);
  finalize_kernel<<<1, 128, 0, stream>>>(gsum3, gsq3, g3, be3, scale3, shift3, 128);
  maxpool_kernel<<<BATCH*(SPTS/16), 256, 0, stream>>>(y3, scale3, shift3, out1);
}

// Round 12
// 2701.954 us; speedup vs baseline: 3.8394x; 3.8394x over previous
//
#include <hip/hip_runtime.h>
#include <hip/hip_bf16.h>
#include <stdint.h>

#define BATCH 8
#define NPTS  16384
#define DIMF  64
#define SPTS  1024
#define NSAMP 32
#define MTOT  (BATCH*SPTS*NSAMP)   // 262144

__device__ __forceinline__ float bfu_lo(uint32_t u){ return __uint_as_float(u<<16); }
__device__ __forceinline__ float bfu_hi(uint32_t u){ return __uint_as_float(u & 0xffff0000u); }
__device__ __forceinline__ uint16_t f2bf(float f){
  __hip_bfloat16 h = __float2bfloat16(f);
  uint16_t u; __builtin_memcpy(&u, &h, 2); return u;
}

// ---------------- prep: transpose points (B,64,N)->(B,N,64) ----------------
__global__ __launch_bounds__(256) void transpose_kernel(const float* __restrict__ pts,
                                                        float* __restrict__ ptsT){
  __shared__ float tile[32][33];
  int b = blockIdx.z;
  int n0 = blockIdx.x*32, c0 = blockIdx.y*32;
  int tx = threadIdx.x & 31, ty = threadIdx.x >> 5;
  const float* src = pts + (size_t)b*DIMF*NPTS;
  float* dst = ptsT + (size_t)b*NPTS*DIMF;
#pragma unroll
  for (int j=0;j<4;j++)
    tile[ty+8*j][tx] = src[(size_t)(c0+ty+8*j)*NPTS + n0 + tx];
  __syncthreads();
#pragma unroll
  for (int j=0;j<4;j++)
    dst[(size_t)(n0+ty+8*j)*DIMF + c0 + tx] = tile[tx][ty+8*j];
}

// ---------------- FPS: R5 skeleton + x,y in LDS ----------------
// R5 (2127us) decomposition: 1536cy VALU + ~3500cy px/py/pz L2 re-reads
// (196KB/iter; VGPR=104 < 128-float state proves arrays not resident).
// Fix: x,y served from LDS (128KB, ds_read_b64 conflict-free, 2x L2 BW);
// z remat from global (64KB/iter); dst (32 regs) stays resident within the
// same ~104-VGPR budget. Reduce/barrier/centroid-load identical to R5
// (2-value shfl, parity dbuf, readfirstlane + scalar X[far] loads).
// Distance arithmetic and first-max tie semantics bit-identical.
__global__ __launch_bounds__(512, 2) void fps_kernel(const float* __restrict__ xyz,
                                                     float* __restrict__ out0){
  int b = blockIdx.x;
  const float* X = xyz + (size_t)b*3*NPTS;
  int t = threadIdx.x;
  int lane = t & 63, wid = t >> 6;   // 8 waves
  __shared__ float2 lxy[NPTS];       // 128 KB
  __shared__ float rv[2][8];
  __shared__ int   ri[2][8];
  float pz[32], dst[32];
#pragma unroll
  for (int k=0;k<32;k++){
    int n = t + (k<<9);
    lxy[n] = make_float2(X[n], X[NPTS+n]);
    pz[k]  = X[2*NPTS+n];
    dst[k] = 1e10f;
  }
  __syncthreads();
  int far = 0;
  float* o = out0 + (size_t)b*3*SPTS;
  for (int s=0;s<SPTS;s++){
    float cx = X[far], cy = X[NPTS+far], cz = X[2*NPTS+far];  // uniform scalar loads
    if (t==0){ o[s]=cx; o[SPTS+s]=cy; o[2*SPTS+s]=cz; }
    if (s==SPTS-1) break;
    float best = -1.0f; int bi = 0x7fffffff;
#pragma unroll
    for (int k=0;k<32;k++){
      int n = t + (k<<9);
      float2 xy = lxy[n];
      float dx=__fsub_rn(xy.x,cx), dy=__fsub_rn(xy.y,cy), dz=__fsub_rn(pz[k],cz);
      float d = __fadd_rn(__fadd_rn(__fmul_rn(dx,dx),__fmul_rn(dy,dy)),__fmul_rn(dz,dz));
      d = fminf(dst[k], d); dst[k] = d;
      if (d > best){ best = d; bi = n; }   // ascending n in k -> first-max
    }
#pragma unroll
    for (int off=1; off<64; off<<=1){
      float ov = __shfl_xor(best, off);
      int   oi = __shfl_xor(bi, off);
      if (ov > best || (ov == best && oi < bi)){ best = ov; bi = oi; }
    }
    int p = s & 1;
    if (lane==0){ rv[p][wid]=best; ri[p][wid]=bi; }
    __syncthreads();
    float v = rv[p][lane&7]; int j = ri[p][lane&7];
#pragma unroll
    for (int off=1; off<8; off<<=1){
      float ov = __shfl_xor(v, off);
      int   oj = __shfl_xor(j, off);
      if (ov > v || (ov == v && oj < j)){ v = ov; j = oj; }
    }
    far = __builtin_amdgcn_readfirstlane(j);   // uniform -> scalar centroid loads
  }
}

// ---------------- ball query: XLA-CPU f32 replication ----------------
// A (query norm), B (point norm): plain sequential ((x^2+y^2)+z^2)  [XLA reduce, no FMA]
// C (dot): Eigen gemm FMA chain fma(z*nz, fma(y*ny, x*nx))          [einsum -> Eigen]
// sqr = (A+B) - 2*C  (x2 exact, fuse-independent)
__global__ __launch_bounds__(256) void ball_kernel(const float* __restrict__ xyz,
                                                   const float* __restrict__ newxyz,
                                                   int* __restrict__ idxo){
  int b  = blockIdx.x >> 5;
  int sc = blockIdx.x & 31;           // 32 s per block
  const float* X  = xyz + (size_t)b*3*NPTS;
  int t = threadIdx.x, lane = t & 63, w = t >> 6;
  __shared__ float lx[512], ly[512], lz[512], ls[512];
  __shared__ int done;
  if (t==0) done = 0;
  const float rsq = 0.01f;
  float nx[8], ny[8], nz[8], sn[8];
  int cnt[8], first[8];
  int sbase = sc*32 + w*8;
#pragma unroll
  for (int q=0;q<8;q++){
    int s = sbase + q;
    nx[q] = newxyz[(size_t)b*3*SPTS + s];
    ny[q] = newxyz[(size_t)b*3*SPTS + SPTS + s];
    nz[q] = newxyz[(size_t)b*3*SPTS + 2*SPTS + s];
    sn[q] = __fadd_rn(__fadd_rn(__fmul_rn(nx[q],nx[q]),__fmul_rn(ny[q],ny[q])),
                      __fmul_rn(nz[q],nz[q]));
    cnt[q]=0; first[q]=0;
  }
  __syncthreads();
  for (int T=0;T<32;T++){
    {
      float ax = X[T*512 + t], ay = X[NPTS + T*512 + t], az = X[2*NPTS + T*512 + t];
      lx[t]=ax; ly[t]=ay; lz[t]=az;
      ls[t] = __fadd_rn(__fadd_rn(__fmul_rn(ax,ax),__fmul_rn(ay,ay)),__fmul_rn(az,az));
      float bx = X[T*512 + t + 256], by = X[NPTS + T*512 + t + 256], bz = X[2*NPTS + T*512 + t + 256];
      lx[t+256]=bx; ly[t+256]=by; lz[t+256]=bz;
      ls[t+256] = __fadd_rn(__fadd_rn(__fmul_rn(bx,bx),__fmul_rn(by,by)),__fmul_rn(bz,bz));
    }
    __syncthreads();
#pragma unroll
    for (int q=0;q<8;q++){
      if (cnt[q] >= NSAMP) continue;
      int s = sbase + q;
      int* op = idxo + ((size_t)(b*SPTS + s))*NSAMP;
      for (int c=0;c<8;c++){
        int li = c*64 + lane;
        float dot = fmaf(nz[q], lz[li], fmaf(ny[q], ly[li], __fmul_rn(nx[q], lx[li])));
        float sq  = __fsub_rn(__fadd_rn(sn[q], ls[li]), __fmul_rn(2.0f, dot));
        bool in = (sq <= rsq);
        unsigned long long m = __ballot(in);
        if (cnt[q]==0 && m) first[q] = T*512 + c*64 + (int)__builtin_ctzll(m);
        if (in){
          int slot = cnt[q] + (int)__popcll(m & ((1ull<<lane)-1ull));
          if (slot < NSAMP) op[slot] = T*512 + li;
        }
        cnt[q] += (int)__popcll(m);
        if (cnt[q] >= NSAMP){ if (lane==0) atomicAdd(&done,1); break; }
      }
    }
    __syncthreads();
    if (done >= 32) break;   // uniform across the block
  }
#pragma unroll
  for (int q=0;q<8;q++){
    if (cnt[q] < NSAMP){
      int s = sbase + q;
      int* op = idxo + ((size_t)(b*SPTS + s))*NSAMP;
      if (lane >= cnt[q] && lane < NSAMP) op[lane] = first[q];
    }
  }
}

// ---------------- GEMM1: fused gather (xyz diff + pts) x w1 -> y1 (bf16) ----------------
__global__ __launch_bounds__(256) void gemm1_kernel(const float* __restrict__ xyz,
                                                    const float* __restrict__ ptsT,
                                                    const int* __restrict__ idx,
                                                    const float* __restrict__ newxyz,
                                                    const float* __restrict__ w1,
                                                    const float* __restrict__ b1,
                                                    uint16_t* __restrict__ y1){
  __shared__ float As[128*69];
  __shared__ float Ws[67*64];
  __shared__ float bias[64];
  __shared__ int   ndx[128];
  __shared__ float nxs[4][3];
  int t = threadIdx.x;
  int g0 = blockIdx.x*128;
  if (t < 128) ndx[t] = idx[g0 + t];
  if (t < 12){
    int grp = t/3, c = t%3;
    int bs = (g0>>5) + grp; int b = bs>>10, s = bs & 1023;
    nxs[grp][c] = newxyz[(size_t)b*3*SPTS + c*SPTS + s];
  }
  if (t < 64) bias[t] = b1[t];
  for (int e=t; e<67*64; e+=256){ int k=e>>6, c=e&63; Ws[k*64+c] = w1[c*67+k]; }
  __syncthreads();
  {
    int r = t>>1, h = t&1;
    int n = ndx[r];
    int bs = (g0>>5) + (r>>5); int b = bs>>10;
    const float* pr = ptsT + ((size_t)(b*NPTS + n))*64 + h*32;
    float* ar = As + r*69;
    if (h==0){
      int grp = r>>5;
      ar[0] = __fsub_rn(xyz[(size_t)b*3*NPTS + n],          nxs[grp][0]);
      ar[1] = __fsub_rn(xyz[(size_t)b*3*NPTS + NPTS + n],   nxs[grp][1]);
      ar[2] = __fsub_rn(xyz[(size_t)b*3*NPTS + 2*NPTS + n], nxs[grp][2]);
    }
    float* ap = ar + 3 + h*32;
#pragma unroll
    for (int j=0;j<8;j++){
      float4 v = *(const float4*)(pr + j*4);
      ap[j*4+0]=v.x; ap[j*4+1]=v.y; ap[j*4+2]=v.z; ap[j*4+3]=v.w;
    }
  }
  __syncthreads();
  int rg = t>>3, cg = t&7;
  float acc[4][8];
#pragma unroll
  for (int i=0;i<4;i++)
#pragma unroll
    for (int j=0;j<8;j++) acc[i][j]=0.f;
  for (int k=0;k<67;k++){
    float a0 = As[(rg*4+0)*69+k];
    float a1 = As[(rg*4+1)*69+k];
    float a2 = As[(rg*4+2)*69+k];
    float a3 = As[(rg*4+3)*69+k];
    const float* wr = Ws + k*64 + cg*8;
    float4 w0 = *(const float4*)wr;
    float4 w1v = *(const float4*)(wr+4);
    float wj[8] = {w0.x,w0.y,w0.z,w0.w,w1v.x,w1v.y,w1v.z,w1v.w};
#pragma unroll
    for (int j=0;j<8;j++){
      acc[0][j] = fmaf(a0, wj[j], acc[0][j]);
      acc[1][j] = fmaf(a1, wj[j], acc[1][j]);
      acc[2][j] = fmaf(a2, wj[j], acc[2][j]);
      acc[3][j] = fmaf(a3, wj[j], acc[3][j]);
    }
  }
#pragma unroll
  for (int i=0;i<4;i++){
    int gr = g0 + rg*4 + i;
    uint16_t* yr = y1 + (size_t)gr*64 + cg*8;
    uint4 vv;
    uint32_t u[4];
#pragma unroll
    for (int j=0;j<4;j++){
      float v0 = acc[i][2*j]   + bias[cg*8+2*j];
      float v1 = acc[i][2*j+1] + bias[cg*8+2*j+1];
      u[j] = (uint32_t)f2bf(v0) | ((uint32_t)f2bf(v1)<<16);
    }
    vv.x=u[0]; vv.y=u[1]; vv.z=u[2]; vv.w=u[3];
    *(uint4*)yr = vv;
  }
}

// ---------------- GEMM2: relu(bn(y1)) x w2 -> y2 (bf16), K=64 ----------------
__global__ __launch_bounds__(256) void gemm2_kernel(const uint16_t* __restrict__ yin,
                                                    const float* __restrict__ w2,
                                                    const float* __restrict__ b2,
                                                    const float* __restrict__ scale,
                                                    const float* __restrict__ shift,
                                                    uint16_t* __restrict__ yout){
  __shared__ float As[128*65];
  __shared__ float Ws[64*64];
  __shared__ float bias[64], sc[64], sh[64];
  int t = threadIdx.x;
  int g0 = blockIdx.x*128;
  if (t < 64){ bias[t]=b2[t]; sc[t]=scale[t]; sh[t]=shift[t]; }
  for (int e=t; e<64*64; e+=256){ int k=e>>6, c=e&63; Ws[k*64+c] = w2[c*64+k]; }
  __syncthreads();
  {
    int r = t>>1, h = t&1;
    const uint4* yv = (const uint4*)(yin + (size_t)(g0+r)*64 + h*32);
    float* ar = As + r*65 + h*32;
#pragma unroll
    for (int j=0;j<4;j++){
      uint4 u = yv[j];
      uint32_t vv[4] = {u.x,u.y,u.z,u.w};
#pragma unroll
      for (int m=0;m<4;m++){
        int c = h*32 + j*8 + m*2;
        ar[j*8+m*2]   = fmaxf(fmaf(bfu_lo(vv[m]), sc[c],   sh[c]),   0.f);
        ar[j*8+m*2+1] = fmaxf(fmaf(bfu_hi(vv[m]), sc[c+1], sh[c+1]), 0.f);
      }
    }
  }
  __syncthreads();
  int rg = t>>3, cg = t&7;
  float acc[4][8];
#pragma unroll
  for (int i=0;i<4;i++)
#pragma unroll
    for (int j=0;j<8;j++) acc[i][j]=0.f;
  for (int k=0;k<64;k++){
    float a0 = As[(rg*4+0)*65+k];
    float a1 = As[(rg*4+1)*65+k];
    float a2 = As[(rg*4+2)*65+k];
    float a3 = As[(rg*4+3)*65+k];
    const float* wr = Ws + k*64 + cg*8;
    float4 w0 = *(const float4*)wr;
    float4 w1v = *(const float4*)(wr+4);
    float wj[8] = {w0.x,w0.y,w0.z,w0.w,w1v.x,w1v.y,w1v.z,w1v.w};
#pragma unroll
    for (int j=0;j<8;j++){
      acc[0][j] = fmaf(a0, wj[j], acc[0][j]);
      acc[1][j] = fmaf(a1, wj[j], acc[1][j]);
      acc[2][j] = fmaf(a2, wj[j], acc[2][j]);
      acc[3][j] = fmaf(a3, wj[j], acc[3][j]);
    }
  }
#pragma unroll
  for (int i=0;i<4;i++){
    int gr = g0 + rg*4 + i;
    uint16_t* yr = yout + (size_t)gr*64 + cg*8;
    uint4 vv; uint32_t u[4];
#pragma unroll
    for (int j=0;j<4;j++){
      float v0 = acc[i][2*j]   + bias[cg*8+2*j];
      float v1 = acc[i][2*j+1] + bias[cg*8+2*j+1];
      u[j] = (uint32_t)f2bf(v0) | ((uint32_t)f2bf(v1)<<16);
    }
    vv.x=u[0]; vv.y=u[1]; vv.z=u[2]; vv.w=u[3];
    *(uint4*)yr = vv;
  }
}

// ---------------- GEMM3: relu(bn(y2)) x w3 -> y3 (bf16), K=64, OUT=128 ----------------
__global__ __launch_bounds__(256) void gemm3_kernel(const uint16_t* __restrict__ yin,
                                                    const float* __restrict__ w3,
                                                    const float* __restrict__ b3,
                                                    const float* __restrict__ scale,
                                                    const float* __restrict__ shift,
                                                    uint16_t* __restrict__ yout){
  __shared__ float As[64*65];
  __shared__ float Ws[64*128];
  __shared__ float bias[128], sc[64], sh[64];
  int t = threadIdx.x;
  int g0 = blockIdx.x*64;
  if (t < 128) bias[t]=b3[t];
  if (t < 64){ sc[t]=scale[t]; sh[t]=shift[t]; }
  for (int e=t; e<64*128; e+=256){ int k=e>>7, c=e&127; Ws[k*128+c] = w3[c*64+k]; }
  __syncthreads();
  {
    int r = t>>2, h = t&3;
    const uint4* yv = (const uint4*)(yin + (size_t)(g0+r)*64 + h*16);
    float* ar = As + r*65 + h*16;
#pragma unroll
    for (int j=0;j<2;j++){
      uint4 u = yv[j];
      uint32_t vv[4] = {u.x,u.y,u.z,u.w};
#pragma unroll
      for (int m=0;m<4;m++){
        int c = h*16 + j*8 + m*2;
        ar[j*8+m*2]   = fmaxf(fmaf(bfu_lo(vv[m]), sc[c],   sh[c]),   0.f);
        ar[j*8+m*2+1] = fmaxf(fmaf(bfu_hi(vv[m]), sc[c+1], sh[c+1]), 0.f);
      }
    }
  }
  __syncthreads();
  int rg = t>>4, cg = t&15;
  float acc[4][8];
#pragma unroll
  for (int i=0;i<4;i++)
#pragma unroll
    for (int j=0;j<8;j++) acc[i][j]=0.f;
  for (int k=0;k<64;k++){
    float a0 = As[(rg*4+0)*65+k];
    float a1 = As[(rg*4+1)*65+k];
    float a2 = As[(rg*4+2)*65+k];
    float a3 = As[(rg*4+3)*65+k];
    const float* wr = Ws + k*128 + cg*8;
    float4 w0 = *(const float4*)wr;
    float4 w1v = *(const float4*)(wr+4);
    float wj[8] = {w0.x,w0.y,w0.z,w0.w,w1v.x,w1v.y,w1v.z,w1v.w};
#pragma unroll
    for (int j=0;j<8;j++){
      acc[0][j] = fmaf(a0, wj[j], acc[0][j]);
      acc[1][j] = fmaf(a1, wj[j], acc[1][j]);
      acc[2][j] = fmaf(a2, wj[j], acc[2][j]);
      acc[3][j] = fmaf(a3, wj[j], acc[3][j]);
    }
  }
#pragma unroll
  for (int i=0;i<4;i++){
    int gr = g0 + rg*4 + i;
    uint16_t* yr = yout + (size_t)gr*128 + cg*8;
    uint4 vv; uint32_t u[4];
#pragma unroll
    for (int j=0;j<4;j++){
      float v0 = acc[i][2*j]   + bias[cg*8+2*j];
      float v1 = acc[i][2*j+1] + bias[cg*8+2*j+1];
      u[j] = (uint32_t)f2bf(v0) | ((uint32_t)f2bf(v1)<<16);
    }
    vv.x=u[0]; vv.y=u[1]; vv.z=u[2]; vv.w=u[3];
    *(uint4*)yr = vv;
  }
}

// ---------------- per-channel stats (sum, sumsq) ----------------
template<int C>
__global__ __launch_bounds__(256) void stats_kernel(const uint16_t* __restrict__ y,
                                                    float* __restrict__ gsum,
                                                    float* __restrict__ gsq){
  constexpr int CP  = C/2;
  constexpr int RSL = 256/CP;
  int t = threadIdx.x;
  int c0 = t % CP, rs = t / CP;
  float s0=0.f,q0=0.f,s1=0.f,q1=0.f;
#pragma unroll 4
  for (int i=0;i<512/RSL;i++){
    int r = blockIdx.x*512 + rs + i*RSL;
    uint32_t u = *(const uint32_t*)(y + (size_t)r*C + 2*c0);
    float v0 = bfu_lo(u), v1 = bfu_hi(u);
    s0 += v0; q0 += v0*v0; s1 += v1; q1 += v1*v1;
  }
  __shared__ float red[4][256];
  red[0][t]=s0; red[1][t]=q0; red[2][t]=s1; red[3][t]=q1;
  __syncthreads();
  if (t < CP){
    float a0=0,a1=0,a2=0,a3=0;
    for (int k=0;k<RSL;k++){
      a0+=red[0][k*CP+t]; a1+=red[1][k*CP+t]; a2+=red[2][k*CP+t]; a3+=red[3][k*CP+t];
    }
    atomicAdd(&gsum[2*t],   a0); atomicAdd(&gsq[2*t],   a1);
    atomicAdd(&gsum[2*t+1], a2); atomicAdd(&gsq[2*t+1], a3);
  }
}

__global__ void finalize_kernel(const float* __restrict__ gsum, const float* __restrict__ gsq,
                                const float* __restrict__ g, const float* __restrict__ be,
                                float* __restrict__ scale, float* __restrict__ shift, int C){
  int c = threadIdx.x;
  if (c >= C) return;
  double mean = (double)gsum[c] / (double)MTOT;
  double var  = (double)gsq[c] / (double)MTOT - mean*mean;
  double s    = (double)g[c] / sqrt(var + 1e-5);
  scale[c] = (float)s;
  shift[c] = (float)((double)be[c] - mean*s);
}

// ---------------- bn3 + relu + maxpool over nsample + transpose ----------------
__global__ __launch_bounds__(256) void maxpool_kernel(const uint16_t* __restrict__ y3,
                                                      const float* __restrict__ scale,
                                                      const float* __restrict__ shift,
                                                      float* __restrict__ out1){
  __shared__ float tr[16][129];
  int t = threadIdx.x;
  int b = blockIdx.x >> 6;
  int s0 = (blockIdx.x & 63) * 16;
  int ch = t & 127, sl0 = t >> 7;
  float scv = scale[ch], shv = shift[ch];
  for (int sl=sl0; sl<16; sl+=2){
    int bs = b*SPTS + s0 + sl;
    const uint16_t* yr = y3 + (size_t)bs*NSAMP*128 + ch;
    float m = 0.0f;
#pragma unroll 4
    for (int k=0;k<NSAMP;k++){
      float v = __uint_as_float(((uint32_t)yr[k*128])<<16);
      float z = fmaxf(fmaf(v, scv, shv), 0.f);
      m = fmaxf(m, z);
    }
    tr[sl][ch] = m;
  }
  __syncthreads();
  int ch2 = t >> 1, hh = t & 1;
  float vals[8];
#pragma unroll
  for (int i=0;i<8;i++) vals[i] = tr[hh*8+i][ch2];
  float* op = out1 + (size_t)b*131072 + (size_t)ch2*1024 + s0 + hh*8;
  float4 v0; v0.x=vals[0]; v0.y=vals[1]; v0.z=vals[2]; v0.w=vals[3];
  float4 v1; v1.x=vals[4]; v1.y=vals[5]; v1.z=vals[6]; v1.w=vals[7];
  *(float4*)op = v0;
  *(float4*)(op+4) = v1;
}

extern "C" void kernel_launch(void* const* d_in, const int* in_sizes, int n_in,
                              void* d_out, int out_size, void* d_ws, size_t ws_size,
                              hipStream_t stream){
  (void)in_sizes; (void)n_in; (void)out_size; (void)ws_size;
  const float* xyz = (const float*)d_in[0];
  const float* pts = (const float*)d_in[1];
  const float* w1 = (const float*)d_in[2];  const float* b1 = (const float*)d_in[3];
  const float* g1 = (const float*)d_in[4];  const float* be1 = (const float*)d_in[5];
  const float* w2 = (const float*)d_in[6];  const float* b2 = (const float*)d_in[7];
  const float* g2 = (const float*)d_in[8];  const float* be2 = (const float*)d_in[9];
  const float* w3 = (const float*)d_in[10]; const float* b3 = (const float*)d_in[11];
  const float* g3 = (const float*)d_in[12]; const float* be3 = (const float*)d_in[13];

  float* out0 = (float*)d_out;                 // (B,3,1024)
  float* out1 = out0 + BATCH*3*SPTS;           // (B,128,1024)

  char* ws = (char*)d_ws;
  float*    ptsT = (float*)(ws + 0);                       // 33,554,432 B
  int*      idx  = (int*)  (ws + 34078720);                //  1,048,576 B
  uint16_t* y1   = (uint16_t*)(ws + 35127296);             // 33,554,432 B
  uint16_t* y2   = (uint16_t*)(ws + 68681728);             // 33,554,432 B
  uint16_t* y3   = (uint16_t*)(ws + 102236160);            // 67,108,864 B
  float*    stats = (float*)(ws + 169345024);              // 1536 floats
  float* gsum1 = stats;        float* gsq1 = stats + 128;
  float* gsum2 = stats + 256;  float* gsq2 = stats + 384;
  float* gsum3 = stats + 512;  float* gsq3 = stats + 640;
  float* scale1 = stats + 768; float* shift1 = stats + 896;
  float* scale2 = stats + 1024; float* shift2 = stats + 1152;
  float* scale3 = stats + 1280; float* shift3 = stats + 1408;

  hipMemsetAsync(stats, 0, 768*sizeof(float), stream);

  transpose_kernel<<<dim3(NPTS/32, DIMF/32, BATCH), 256, 0, stream>>>(pts, ptsT);
  fps_kernel<<<BATCH, 512, 0, stream>>>(xyz, out0);
  ball_kernel<<<BATCH*32, 256, 0, stream>>>(xyz, out0, idx);
  gemm1_kernel<<<MTOT/128, 256, 0, stream>>>(xyz, ptsT, idx, out0, w1, b1, y1);
  stats_kernel<64><<<512, 256, 0, stream>>>(y1, gsum1, gsq1);
  finalize_kernel<<<1, 128, 0, stream>>>(gsum1, gsq1, g1, be1, scale1, shift1, 64);
  gemm2_kernel<<<MTOT/128, 256, 0, stream>>>(y1, w2, b2, scale1, shift1, y2);
  stats_kernel<64><<<512, 256, 0, stream>>>(y2, gsum2, gsq2);
  finalize_kernel<<<1, 128, 0, stream>>>(gsum2, gsq2, g2, be2, scale2, shift2, 64);
  gemm3_kernel<<<MTOT/64, 256, 0, stream>>>(y2, w3, b3, scale2, shift2, y3);
  stats_kernel<128><<<512, 256, 0, stream>>>(y3, gsum3, gsq3);
  finalize_kernel<<<1, 128, 0, stream>>>(gsum3, gsq3, g3, be3, scale3, shift3, 128);
  maxpool_kernel<<<BATCH*(SPTS/16), 256, 0, stream>>>(y3, scale3, shift3, out1);
}

// Round 13
// 2660.282 us; speedup vs baseline: 3.8995x; 1.0157x over previous
//
#include <hip/hip_runtime.h>
#include <hip/hip_bf16.h>
#include <stdint.h>

#define BATCH 8
#define NPTS  16384
#define DIMF  64
#define SPTS  1024
#define NSAMP 32
#define MTOT  (BATCH*SPTS*NSAMP)   // 262144

__device__ __forceinline__ float bfu_lo(uint32_t u){ return __uint_as_float(u<<16); }
__device__ __forceinline__ float bfu_hi(uint32_t u){ return __uint_as_float(u & 0xffff0000u); }
__device__ __forceinline__ uint16_t f2bf(float f){
  __hip_bfloat16 h = __float2bfloat16(f);
  uint16_t u; __builtin_memcpy(&u, &h, 2); return u;
}

// ---------------- prep: transpose points (B,64,N)->(B,N,64) ----------------
__global__ __launch_bounds__(256) void transpose_kernel(const float* __restrict__ pts,
                                                        float* __restrict__ ptsT){
  __shared__ float tile[32][33];
  int b = blockIdx.z;
  int n0 = blockIdx.x*32, c0 = blockIdx.y*32;
  int tx = threadIdx.x & 31, ty = threadIdx.x >> 5;
  const float* src = pts + (size_t)b*DIMF*NPTS;
  float* dst = ptsT + (size_t)b*NPTS*DIMF;
#pragma unroll
  for (int j=0;j<4;j++)
    tile[ty+8*j][tx] = src[(size_t)(c0+ty+8*j)*NPTS + n0 + tx];
  __syncthreads();
#pragma unroll
  for (int j=0;j<4;j++)
    dst[(size_t)(n0+ty+8*j)*DIMF + c0 + tx] = tile[tx][ty+8*j];
}

// ---------------- FPS: R5 variant (best measured: 2127us), verbatim ----------------
__global__ __launch_bounds__(512, 2) void fps_kernel(const float* __restrict__ xyz,
                                                     float* __restrict__ out0){
  int b = blockIdx.x;
  const float* X = xyz + (size_t)b*3*NPTS;
  int t = threadIdx.x;
  int lane = t & 63, wid = t >> 6;   // 8 waves
  float px[32], py[32], pz[32], dst[32];
#pragma unroll
  for (int k=0;k<32;k++){
    int n = t + (k<<9);
    px[k]=X[n]; py[k]=X[NPTS+n]; pz[k]=X[2*NPTS+n];
    dst[k]=1e10f;
  }
  __shared__ float rv[2][8];
  __shared__ int   ri[2][8];
  int far = 0;
  float* o = out0 + (size_t)b*3*SPTS;
  for (int s=0;s<SPTS;s++){
    float cx = X[far], cy = X[NPTS+far], cz = X[2*NPTS+far];
    if (t==0){ o[s]=cx; o[SPTS+s]=cy; o[2*SPTS+s]=cz; }
    if (s==SPTS-1) break;
    float best = -1.0f; int bi = 0x7fffffff;
#pragma unroll
    for (int k=0;k<32;k++){
      float dx=__fsub_rn(px[k],cx), dy=__fsub_rn(py[k],cy), dz=__fsub_rn(pz[k],cz);
      float d = __fadd_rn(__fadd_rn(__fmul_rn(dx,dx),__fmul_rn(dy,dy)),__fmul_rn(dz,dz));
      d = fminf(dst[k], d); dst[k] = d;
      if (d > best){ best = d; bi = t + (k<<9); }   // ascending n in k -> first-max
    }
#pragma unroll
    for (int off=1; off<64; off<<=1){
      float ov = __shfl_xor(best, off);
      int   oi = __shfl_xor(bi, off);
      if (ov > best || (ov == best && oi < bi)){ best = ov; bi = oi; }
    }
    int p = s & 1;
    if (lane==0){ rv[p][wid]=best; ri[p][wid]=bi; }
    __syncthreads();
    float v = rv[p][lane&7]; int j = ri[p][lane&7];
#pragma unroll
    for (int off=1; off<8; off<<=1){
      float ov = __shfl_xor(v, off);
      int   oj = __shfl_xor(j, off);
      if (ov > v || (ov == v && oj < j)){ v = ov; j = oj; }
    }
    far = j;   // identical in every lane/wave
  }
}

// ---------------- ball query: XLA-CPU f32 replication ----------------
__global__ __launch_bounds__(256) void ball_kernel(const float* __restrict__ xyz,
                                                   const float* __restrict__ newxyz,
                                                   int* __restrict__ idxo){
  int b  = blockIdx.x >> 5;
  int sc = blockIdx.x & 31;           // 32 s per block
  const float* X  = xyz + (size_t)b*3*NPTS;
  int t = threadIdx.x, lane = t & 63, w = t >> 6;
  __shared__ float lx[512], ly[512], lz[512], ls[512];
  __shared__ int done;
  if (t==0) done = 0;
  const float rsq = 0.01f;
  float nx[8], ny[8], nz[8], sn[8];
  int cnt[8], first[8];
  int sbase = sc*32 + w*8;
#pragma unroll
  for (int q=0;q<8;q++){
    int s = sbase + q;
    nx[q] = newxyz[(size_t)b*3*SPTS + s];
    ny[q] = newxyz[(size_t)b*3*SPTS + SPTS + s];
    nz[q] = newxyz[(size_t)b*3*SPTS + 2*SPTS + s];
    sn[q] = __fadd_rn(__fadd_rn(__fmul_rn(nx[q],nx[q]),__fmul_rn(ny[q],ny[q])),
                      __fmul_rn(nz[q],nz[q]));
    cnt[q]=0; first[q]=0;
  }
  __syncthreads();
  for (int T=0;T<32;T++){
    {
      float ax = X[T*512 + t], ay = X[NPTS + T*512 + t], az = X[2*NPTS + T*512 + t];
      lx[t]=ax; ly[t]=ay; lz[t]=az;
      ls[t] = __fadd_rn(__fadd_rn(__fmul_rn(ax,ax),__fmul_rn(ay,ay)),__fmul_rn(az,az));
      float bx = X[T*512 + t + 256], by = X[NPTS + T*512 + t + 256], bz = X[2*NPTS + T*512 + t + 256];
      lx[t+256]=bx; ly[t+256]=by; lz[t+256]=bz;
      ls[t+256] = __fadd_rn(__fadd_rn(__fmul_rn(bx,bx),__fmul_rn(by,by)),__fmul_rn(bz,bz));
    }
    __syncthreads();
#pragma unroll
    for (int q=0;q<8;q++){
      if (cnt[q] >= NSAMP) continue;
      int s = sbase + q;
      int* op = idxo + ((size_t)(b*SPTS + s))*NSAMP;
      for (int c=0;c<8;c++){
        int li = c*64 + lane;
        float dot = fmaf(nz[q], lz[li], fmaf(ny[q], ly[li], __fmul_rn(nx[q], lx[li])));
        float sq  = __fsub_rn(__fadd_rn(sn[q], ls[li]), __fmul_rn(2.0f, dot));
        bool in = (sq <= rsq);
        unsigned long long m = __ballot(in);
        if (cnt[q]==0 && m) first[q] = T*512 + c*64 + (int)__builtin_ctzll(m);
        if (in){
          int slot = cnt[q] + (int)__popcll(m & ((1ull<<lane)-1ull));
          if (slot < NSAMP) op[slot] = T*512 + li;
        }
        cnt[q] += (int)__popcll(m);
        if (cnt[q] >= NSAMP){ if (lane==0) atomicAdd(&done,1); break; }
      }
    }
    __syncthreads();
    if (done >= 32) break;   // uniform across the block
  }
#pragma unroll
  for (int q=0;q<8;q++){
    if (cnt[q] < NSAMP){
      int s = sbase + q;
      int* op = idxo + ((size_t)(b*SPTS + s))*NSAMP;
      if (lane >= cnt[q] && lane < NSAMP) op[lane] = first[q];
    }
  }
}

// ---------------- GEMM1: gather x w1 -> y1 (bf16) + fused per-channel stats ----------------
__global__ __launch_bounds__(256) void gemm1_kernel(const float* __restrict__ xyz,
                                                    const float* __restrict__ ptsT,
                                                    const int* __restrict__ idx,
                                                    const float* __restrict__ newxyz,
                                                    const float* __restrict__ w1,
                                                    const float* __restrict__ b1,
                                                    uint16_t* __restrict__ y1,
                                                    float* __restrict__ gsum,
                                                    float* __restrict__ gsq){
  __shared__ float As[128*69];     // reused as stats scratch in epilogue
  __shared__ float Ws[67*64];
  __shared__ float bias[64];
  __shared__ int   ndx[128];
  __shared__ float nxs[4][3];
  int t = threadIdx.x;
  int g0 = blockIdx.x*128;
  if (t < 128) ndx[t] = idx[g0 + t];
  if (t < 12){
    int grp = t/3, c = t%3;
    int bs = (g0>>5) + grp; int b = bs>>10, s = bs & 1023;
    nxs[grp][c] = newxyz[(size_t)b*3*SPTS + c*SPTS + s];
  }
  if (t < 64) bias[t] = b1[t];
  for (int e=t; e<67*64; e+=256){ int k=e>>6, c=e&63; Ws[k*64+c] = w1[c*67+k]; }
  __syncthreads();
  {
    int r = t>>1, h = t&1;
    int n = ndx[r];
    int bs = (g0>>5) + (r>>5); int b = bs>>10;
    const float* pr = ptsT + ((size_t)(b*NPTS + n))*64 + h*32;
    float* ar = As + r*69;
    if (h==0){
      int grp = r>>5;
      ar[0] = __fsub_rn(xyz[(size_t)b*3*NPTS + n],          nxs[grp][0]);
      ar[1] = __fsub_rn(xyz[(size_t)b*3*NPTS + NPTS + n],   nxs[grp][1]);
      ar[2] = __fsub_rn(xyz[(size_t)b*3*NPTS + 2*NPTS + n], nxs[grp][2]);
    }
    float* ap = ar + 3 + h*32;
#pragma unroll
    for (int j=0;j<8;j++){
      float4 v = *(const float4*)(pr + j*4);
      ap[j*4+0]=v.x; ap[j*4+1]=v.y; ap[j*4+2]=v.z; ap[j*4+3]=v.w;
    }
  }
  __syncthreads();
  int rg = t>>3, cg = t&7;
  float acc[4][8];
#pragma unroll
  for (int i=0;i<4;i++)
#pragma unroll
    for (int j=0;j<8;j++) acc[i][j]=0.f;
  for (int k=0;k<67;k++){
    float a0 = As[(rg*4+0)*69+k];
    float a1 = As[(rg*4+1)*69+k];
    float a2 = As[(rg*4+2)*69+k];
    float a3 = As[(rg*4+3)*69+k];
    const float* wr = Ws + k*64 + cg*8;
    float4 w0 = *(const float4*)wr;
    float4 w1v = *(const float4*)(wr+4);
    float wj[8] = {w0.x,w0.y,w0.z,w0.w,w1v.x,w1v.y,w1v.z,w1v.w};
#pragma unroll
    for (int j=0;j<8;j++){
      acc[0][j] = fmaf(a0, wj[j], acc[0][j]);
      acc[1][j] = fmaf(a1, wj[j], acc[1][j]);
      acc[2][j] = fmaf(a2, wj[j], acc[2][j]);
      acc[3][j] = fmaf(a3, wj[j], acc[3][j]);
    }
  }
  float ps[8], pq[8];
#pragma unroll
  for (int j=0;j<8;j++){ ps[j]=0.f; pq[j]=0.f; }
#pragma unroll
  for (int i=0;i<4;i++){
    int gr = g0 + rg*4 + i;
    uint16_t* yr = y1 + (size_t)gr*64 + cg*8;
    uint4 vv; uint32_t u[4]; float vj[8];
#pragma unroll
    for (int j=0;j<8;j++){
      vj[j] = acc[i][j] + bias[cg*8+j];
      ps[j] += vj[j]; pq[j] += vj[j]*vj[j];
    }
#pragma unroll
    for (int j=0;j<4;j++)
      u[j] = (uint32_t)f2bf(vj[2*j]) | ((uint32_t)f2bf(vj[2*j+1])<<16);
    vv.x=u[0]; vv.y=u[1]; vv.z=u[2]; vv.w=u[3];
    *(uint4*)yr = vv;
  }
  __syncthreads();                 // all As reads done -> reuse as red[]
  float* red = As;                 // [32][65] sums, +2080 sq
#pragma unroll
  for (int j=0;j<8;j++){
    red[rg*65 + cg*8 + j]        = ps[j];
    red[2080 + rg*65 + cg*8 + j] = pq[j];
  }
  __syncthreads();
  if (t < 64){
    float s=0.f, q=0.f;
    for (int r=0;r<32;r++){ s += red[r*65+t]; q += red[2080 + r*65 + t]; }
    atomicAdd(&gsum[t], s); atomicAdd(&gsq[t], q);
  }
}

// ---------------- GEMM2: relu(bn(y1)) x w2 -> y2 + fused finalize-in + stats-out ----------------
__global__ __launch_bounds__(256) void gemm2_kernel(const uint16_t* __restrict__ yin,
                                                    const float* __restrict__ w2,
                                                    const float* __restrict__ b2,
                                                    const float* __restrict__ gsumi,
                                                    const float* __restrict__ gsqi,
                                                    const float* __restrict__ gi,
                                                    const float* __restrict__ bei,
                                                    uint16_t* __restrict__ yout,
                                                    float* __restrict__ gsum,
                                                    float* __restrict__ gsq){
  __shared__ float As[128*65];     // reused as stats scratch in epilogue
  __shared__ float Ws[64*64];
  __shared__ float bias[64], sc[64], sh[64];
  int t = threadIdx.x;
  int g0 = blockIdx.x*128;
  if (t < 64){
    bias[t]=b2[t];
    double mean = (double)gsumi[t] / (double)MTOT;
    double var  = (double)gsqi[t] / (double)MTOT - mean*mean;
    double sv   = (double)gi[t] / sqrt(var + 1e-5);
    sc[t] = (float)sv;
    sh[t] = (float)((double)bei[t] - mean*sv);
  }
  for (int e=t; e<64*64; e+=256){ int k=e>>6, c=e&63; Ws[k*64+c] = w2[c*64+k]; }
  __syncthreads();
  {
    int r = t>>1, h = t&1;
    const uint4* yv = (const uint4*)(yin + (size_t)(g0+r)*64 + h*32);
    float* ar = As + r*65 + h*32;
#pragma unroll
    for (int j=0;j<4;j++){
      uint4 u = yv[j];
      uint32_t vv[4] = {u.x,u.y,u.z,u.w};
#pragma unroll
      for (int m=0;m<4;m++){
        int c = h*32 + j*8 + m*2;
        ar[j*8+m*2]   = fmaxf(fmaf(bfu_lo(vv[m]), sc[c],   sh[c]),   0.f);
        ar[j*8+m*2+1] = fmaxf(fmaf(bfu_hi(vv[m]), sc[c+1], sh[c+1]), 0.f);
      }
    }
  }
  __syncthreads();
  int rg = t>>3, cg = t&7;
  float acc[4][8];
#pragma unroll
  for (int i=0;i<4;i++)
#pragma unroll
    for (int j=0;j<8;j++) acc[i][j]=0.f;
  for (int k=0;k<64;k++){
    float a0 = As[(rg*4+0)*65+k];
    float a1 = As[(rg*4+1)*65+k];
    float a2 = As[(rg*4+2)*65+k];
    float a3 = As[(rg*4+3)*65+k];
    const float* wr = Ws + k*64 + cg*8;
    float4 w0 = *(const float4*)wr;
    float4 w1v = *(const float4*)(wr+4);
    float wj[8] = {w0.x,w0.y,w0.z,w0.w,w1v.x,w1v.y,w1v.z,w1v.w};
#pragma unroll
    for (int j=0;j<8;j++){
      acc[0][j] = fmaf(a0, wj[j], acc[0][j]);
      acc[1][j] = fmaf(a1, wj[j], acc[1][j]);
      acc[2][j] = fmaf(a2, wj[j], acc[2][j]);
      acc[3][j] = fmaf(a3, wj[j], acc[3][j]);
    }
  }
  float ps[8], pq[8];
#pragma unroll
  for (int j=0;j<8;j++){ ps[j]=0.f; pq[j]=0.f; }
#pragma unroll
  for (int i=0;i<4;i++){
    int gr = g0 + rg*4 + i;
    uint16_t* yr = yout + (size_t)gr*64 + cg*8;
    uint4 vv; uint32_t u[4]; float vj[8];
#pragma unroll
    for (int j=0;j<8;j++){
      vj[j] = acc[i][j] + bias[cg*8+j];
      ps[j] += vj[j]; pq[j] += vj[j]*vj[j];
    }
#pragma unroll
    for (int j=0;j<4;j++)
      u[j] = (uint32_t)f2bf(vj[2*j]) | ((uint32_t)f2bf(vj[2*j+1])<<16);
    vv.x=u[0]; vv.y=u[1]; vv.z=u[2]; vv.w=u[3];
    *(uint4*)yr = vv;
  }
  __syncthreads();
  float* red = As;
#pragma unroll
  for (int j=0;j<8;j++){
    red[rg*65 + cg*8 + j]        = ps[j];
    red[2080 + rg*65 + cg*8 + j] = pq[j];
  }
  __syncthreads();
  if (t < 64){
    float s=0.f, q=0.f;
    for (int r=0;r<32;r++){ s += red[r*65+t]; q += red[2080 + r*65 + t]; }
    atomicAdd(&gsum[t], s); atomicAdd(&gsq[t], q);
  }
}

// ---------------- GEMM3: relu(bn(y2)) x w3 -> y3 + fused finalize-in + stats-out ----------------
__global__ __launch_bounds__(256) void gemm3_kernel(const uint16_t* __restrict__ yin,
                                                    const float* __restrict__ w3,
                                                    const float* __restrict__ b3,
                                                    const float* __restrict__ gsumi,
                                                    const float* __restrict__ gsqi,
                                                    const float* __restrict__ gi,
                                                    const float* __restrict__ bei,
                                                    uint16_t* __restrict__ yout,
                                                    float* __restrict__ gsum,
                                                    float* __restrict__ gsq){
  __shared__ float As[64*65];      // reused as stats scratch (needs 2*16*129=4128 <= 4160)
  __shared__ float Ws[64*128];
  __shared__ float bias[128], sc[64], sh[64];
  int t = threadIdx.x;
  int g0 = blockIdx.x*64;
  if (t < 128) bias[t]=b3[t];
  if (t < 64){
    double mean = (double)gsumi[t] / (double)MTOT;
    double var  = (double)gsqi[t] / (double)MTOT - mean*mean;
    double sv   = (double)gi[t] / sqrt(var + 1e-5);
    sc[t] = (float)sv;
    sh[t] = (float)((double)bei[t] - mean*sv);
  }
  for (int e=t; e<64*128; e+=256){ int k=e>>7, c=e&127; Ws[k*128+c] = w3[c*64+k]; }
  __syncthreads();
  {
    int r = t>>2, h = t&3;
    const uint4* yv = (const uint4*)(yin + (size_t)(g0+r)*64 + h*16);
    float* ar = As + r*65 + h*16;
#pragma unroll
    for (int j=0;j<2;j++){
      uint4 u = yv[j];
      uint32_t vv[4] = {u.x,u.y,u.z,u.w};
#pragma unroll
      for (int m=0;m<4;m++){
        int c = h*16 + j*8 + m*2;
        ar[j*8+m*2]   = fmaxf(fmaf(bfu_lo(vv[m]), sc[c],   sh[c]),   0.f);
        ar[j*8+m*2+1] = fmaxf(fmaf(bfu_hi(vv[m]), sc[c+1], sh[c+1]), 0.f);
      }
    }
  }
  __syncthreads();
  int rg = t>>4, cg = t&15;
  float acc[4][8];
#pragma unroll
  for (int i=0;i<4;i++)
#pragma unroll
    for (int j=0;j<8;j++) acc[i][j]=0.f;
  for (int k=0;k<64;k++){
    float a0 = As[(rg*4+0)*65+k];
    float a1 = As[(rg*4+1)*65+k];
    float a2 = As[(rg*4+2)*65+k];
    float a3 = As[(rg*4+3)*65+k];
    const float* wr = Ws + k*128 + cg*8;
    float4 w0 = *(const float4*)wr;
    float4 w1v = *(const float4*)(wr+4);
    float wj[8] = {w0.x,w0.y,w0.z,w0.w,w1v.x,w1v.y,w1v.z,w1v.w};
#pragma unroll
    for (int j=0;j<8;j++){
      acc[0][j] = fmaf(a0, wj[j], acc[0][j]);
      acc[1][j] = fmaf(a1, wj[j], acc[1][j]);
      acc[2][j] = fmaf(a2, wj[j], acc[2][j]);
      acc[3][j] = fmaf(a3, wj[j], acc[3][j]);
    }
  }
  float ps[8], pq[8];
#pragma unroll
  for (int j=0;j<8;j++){ ps[j]=0.f; pq[j]=0.f; }
#pragma unroll
  for (int i=0;i<4;i++){
    int gr = g0 + rg*4 + i;
    uint16_t* yr = yout + (size_t)gr*128 + cg*8;
    uint4 vv; uint32_t u[4]; float vj[8];
#pragma unroll
    for (int j=0;j<8;j++){
      vj[j] = acc[i][j] + bias[cg*8+j];
      ps[j] += vj[j]; pq[j] += vj[j]*vj[j];
    }
#pragma unroll
    for (int j=0;j<4;j++)
      u[j] = (uint32_t)f2bf(vj[2*j]) | ((uint32_t)f2bf(vj[2*j+1])<<16);
    vv.x=u[0]; vv.y=u[1]; vv.z=u[2]; vv.w=u[3];
    *(uint4*)yr = vv;
  }
  __syncthreads();
  float* red = As;                 // [16][129] sums, +2064 sq
#pragma unroll
  for (int j=0;j<8;j++){
    red[rg*129 + cg*8 + j]        = ps[j];
    red[2064 + rg*129 + cg*8 + j] = pq[j];
  }
  __syncthreads();
  if (t < 128){
    float s=0.f, q=0.f;
    for (int r=0;r<16;r++){ s += red[r*129+t]; q += red[2064 + r*129 + t]; }
    atomicAdd(&gsum[t], s); atomicAdd(&gsq[t], q);
  }
}

// ---------------- bn3(finalized in-kernel) + relu + maxpool + transpose ----------------
__global__ __launch_bounds__(256) void maxpool_kernel(const uint16_t* __restrict__ y3,
                                                      const float* __restrict__ gsumi,
                                                      const float* __restrict__ gsqi,
                                                      const float* __restrict__ gi,
                                                      const float* __restrict__ bei,
                                                      float* __restrict__ out1){
  __shared__ float tr[16][129];
  __shared__ float scs[128], shs[128];
  int t = threadIdx.x;
  int b = blockIdx.x >> 6;
  int s0 = (blockIdx.x & 63) * 16;
  if (t < 128){
    double mean = (double)gsumi[t] / (double)MTOT;
    double var  = (double)gsqi[t] / (double)MTOT - mean*mean;
    double sv   = (double)gi[t] / sqrt(var + 1e-5);
    scs[t] = (float)sv;
    shs[t] = (float)((double)bei[t] - mean*sv);
  }
  __syncthreads();
  int ch = t & 127, sl0 = t >> 7;
  float scv = scs[ch], shv = shs[ch];
  for (int sl=sl0; sl<16; sl+=2){
    int bs = b*SPTS + s0 + sl;
    const uint16_t* yr = y3 + (size_t)bs*NSAMP*128 + ch;
    float m = 0.0f;
#pragma unroll 4
    for (int k=0;k<NSAMP;k++){
      float v = __uint_as_float(((uint32_t)yr[k*128])<<16);
      float z = fmaxf(fmaf(v, scv, shv), 0.f);
      m = fmaxf(m, z);
    }
    tr[sl][ch] = m;
  }
  __syncthreads();
  int ch2 = t >> 1, hh = t & 1;
  float vals[8];
#pragma unroll
  for (int i=0;i<8;i++) vals[i] = tr[hh*8+i][ch2];
  float* op = out1 + (size_t)b*131072 + (size_t)ch2*1024 + s0 + hh*8;
  float4 v0; v0.x=vals[0]; v0.y=vals[1]; v0.z=vals[2]; v0.w=vals[3];
  float4 v1; v1.x=vals[4]; v1.y=vals[5]; v1.z=vals[6]; v1.w=vals[7];
  *(float4*)op = v0;
  *(float4*)(op+4) = v1;
}

extern "C" void kernel_launch(void* const* d_in, const int* in_sizes, int n_in,
                              void* d_out, int out_size, void* d_ws, size_t ws_size,
                              hipStream_t stream){
  (void)in_sizes; (void)n_in; (void)out_size; (void)ws_size;
  const float* xyz = (const float*)d_in[0];
  const float* pts = (const float*)d_in[1];
  const float* w1 = (const float*)d_in[2];  const float* b1 = (const float*)d_in[3];
  const float* g1 = (const float*)d_in[4];  const float* be1 = (const float*)d_in[5];
  const float* w2 = (const float*)d_in[6];  const float* b2 = (const float*)d_in[7];
  const float* g2 = (const float*)d_in[8];  const float* be2 = (const float*)d_in[9];
  const float* w3 = (const float*)d_in[10]; const float* b3 = (const float*)d_in[11];
  const float* g3 = (const float*)d_in[12]; const float* be3 = (const float*)d_in[13];

  float* out0 = (float*)d_out;                 // (B,3,1024)
  float* out1 = out0 + BATCH*3*SPTS;           // (B,128,1024)

  char* ws = (char*)d_ws;
  float*    ptsT = (float*)(ws + 0);                       // 33,554,432 B
  int*      idx  = (int*)  (ws + 34078720);                //  1,048,576 B
  uint16_t* y1   = (uint16_t*)(ws + 35127296);             // 33,554,432 B
  uint16_t* y2   = (uint16_t*)(ws + 68681728);             // 33,554,432 B
  uint16_t* y3   = (uint16_t*)(ws + 102236160);            // 67,108,864 B
  float*    stats = (float*)(ws + 169345024);              // gsum/gsq x3
  float* gsum1 = stats;        float* gsq1 = stats + 128;
  float* gsum2 = stats + 256;  float* gsq2 = stats + 384;
  float* gsum3 = stats + 512;  float* gsq3 = stats + 640;

  hipMemsetAsync(stats, 0, 768*sizeof(float), stream);

  transpose_kernel<<<dim3(NPTS/32, DIMF/32, BATCH), 256, 0, stream>>>(pts, ptsT);
  fps_kernel<<<BATCH, 512, 0, stream>>>(xyz, out0);
  ball_kernel<<<BATCH*32, 256, 0, stream>>>(xyz, out0, idx);
  gemm1_kernel<<<MTOT/128, 256, 0, stream>>>(xyz, ptsT, idx, out0, w1, b1, y1, gsum1, gsq1);
  gemm2_kernel<<<MTOT/128, 256, 0, stream>>>(y1, w2, b2, gsum1, gsq1, g1, be1, y2, gsum2, gsq2);
  gemm3_kernel<<<MTOT/64, 256, 0, stream>>>(y2, w3, b3, gsum2, gsq2, g2, be2, y3, gsum3, gsq3);
  maxpool_kernel<<<BATCH*(SPTS/16), 256, 0, stream>>>(y3, gsum3, gsq3, g3, be3, out1);
}

// Round 14
// 2616.991 us; speedup vs baseline: 3.9640x; 1.0165x over previous
//
#include <hip/hip_runtime.h>
#include <hip/hip_bf16.h>
#include <stdint.h>

#define BATCH 8
#define NPTS  16384
#define DIMF  64
#define SPTS  1024
#define NSAMP 32
#define MTOT  (BATCH*SPTS*NSAMP)   // 262144

__device__ __forceinline__ float bfu_lo(uint32_t u){ return __uint_as_float(u<<16); }
__device__ __forceinline__ float bfu_hi(uint32_t u){ return __uint_as_float(u & 0xffff0000u); }
__device__ __forceinline__ uint16_t f2bf(float f){
  __hip_bfloat16 h = __float2bfloat16(f);
  uint16_t u; __builtin_memcpy(&u, &h, 2); return u;
}

// ---------------- FPS (R5 variant, best measured 2125us) + transpose folded in ----------------
// Blocks 0..7: serial FPS, one per batch (unchanged code path).
// Blocks 8..2055: (B,64,N)->(B,N,64) transpose of `pts` in 64x64 LDS tiles,
// running on the otherwise-idle 248 CUs, hidden under the FPS duration.
__global__ __launch_bounds__(512, 2) void fps_kernel(const float* __restrict__ xyz,
                                                     float* __restrict__ out0,
                                                     const float* __restrict__ pts,
                                                     float* __restrict__ ptsT){
  if (blockIdx.x >= BATCH){
    __shared__ float tile[64][65];
    int bb = blockIdx.x - BATCH;       // 0..2047
    int b  = bb >> 8;                  // 256 slabs per batch
    int n0 = (bb & 255) << 6;
    const float* src = pts + (size_t)b*DIMF*NPTS;
    float* dst = ptsT + (size_t)b*NPTS*DIMF;
    int t = threadIdx.x;
    int cn = t & 63, cw = t >> 6;      // 8 groups of 64 lanes
#pragma unroll
    for (int j=0;j<8;j++){
      int c = cw + j*8;
      tile[c][cn] = src[(size_t)c*NPTS + n0 + cn];
    }
    __syncthreads();
#pragma unroll
    for (int j=0;j<8;j++){
      int nl = cw + j*8;
      dst[(size_t)(n0+nl)*DIMF + cn] = tile[cn][nl];
    }
    return;
  }
  int b = blockIdx.x;
  const float* X = xyz + (size_t)b*3*NPTS;
  int t = threadIdx.x;
  int lane = t & 63, wid = t >> 6;   // 8 waves
  float px[32], py[32], pz[32], dst[32];
#pragma unroll
  for (int k=0;k<32;k++){
    int n = t + (k<<9);
    px[k]=X[n]; py[k]=X[NPTS+n]; pz[k]=X[2*NPTS+n];
    dst[k]=1e10f;
  }
  __shared__ float rv[2][8];
  __shared__ int   ri[2][8];
  int far = 0;
  float* o = out0 + (size_t)b*3*SPTS;
  for (int s=0;s<SPTS;s++){
    float cx = X[far], cy = X[NPTS+far], cz = X[2*NPTS+far];
    if (t==0){ o[s]=cx; o[SPTS+s]=cy; o[2*SPTS+s]=cz; }
    if (s==SPTS-1) break;
    float best = -1.0f; int bi = 0x7fffffff;
#pragma unroll
    for (int k=0;k<32;k++){
      float dx=__fsub_rn(px[k],cx), dy=__fsub_rn(py[k],cy), dz=__fsub_rn(pz[k],cz);
      float d = __fadd_rn(__fadd_rn(__fmul_rn(dx,dx),__fmul_rn(dy,dy)),__fmul_rn(dz,dz));
      d = fminf(dst[k], d); dst[k] = d;
      if (d > best){ best = d; bi = t + (k<<9); }   // ascending n in k -> first-max
    }
#pragma unroll
    for (int off=1; off<64; off<<=1){
      float ov = __shfl_xor(best, off);
      int   oi = __shfl_xor(bi, off);
      if (ov > best || (ov == best && oi < bi)){ best = ov; bi = oi; }
    }
    int p = s & 1;
    if (lane==0){ rv[p][wid]=best; ri[p][wid]=bi; }
    __syncthreads();
    float v = rv[p][lane&7]; int j = ri[p][lane&7];
#pragma unroll
    for (int off=1; off<8; off<<=1){
      float ov = __shfl_xor(v, off);
      int   oj = __shfl_xor(j, off);
      if (ov > v || (ov == v && oj < j)){ v = ov; j = oj; }
    }
    far = j;   // identical in every lane/wave
  }
}

// ---------------- ball query: XLA-CPU f32 replication ----------------
__global__ __launch_bounds__(256) void ball_kernel(const float* __restrict__ xyz,
                                                   const float* __restrict__ newxyz,
                                                   int* __restrict__ idxo){
  int b  = blockIdx.x >> 5;
  int sc = blockIdx.x & 31;           // 32 s per block
  const float* X  = xyz + (size_t)b*3*NPTS;
  int t = threadIdx.x, lane = t & 63, w = t >> 6;
  __shared__ float lx[512], ly[512], lz[512], ls[512];
  __shared__ int done;
  if (t==0) done = 0;
  const float rsq = 0.01f;
  float nx[8], ny[8], nz[8], sn[8];
  int cnt[8], first[8];
  int sbase = sc*32 + w*8;
#pragma unroll
  for (int q=0;q<8;q++){
    int s = sbase + q;
    nx[q] = newxyz[(size_t)b*3*SPTS + s];
    ny[q] = newxyz[(size_t)b*3*SPTS + SPTS + s];
    nz[q] = newxyz[(size_t)b*3*SPTS + 2*SPTS + s];
    sn[q] = __fadd_rn(__fadd_rn(__fmul_rn(nx[q],nx[q]),__fmul_rn(ny[q],ny[q])),
                      __fmul_rn(nz[q],nz[q]));
    cnt[q]=0; first[q]=0;
  }
  __syncthreads();
  for (int T=0;T<32;T++){
    {
      float ax = X[T*512 + t], ay = X[NPTS + T*512 + t], az = X[2*NPTS + T*512 + t];
      lx[t]=ax; ly[t]=ay; lz[t]=az;
      ls[t] = __fadd_rn(__fadd_rn(__fmul_rn(ax,ax),__fmul_rn(ay,ay)),__fmul_rn(az,az));
      float bx = X[T*512 + t + 256], by = X[NPTS + T*512 + t + 256], bz = X[2*NPTS + T*512 + t + 256];
      lx[t+256]=bx; ly[t+256]=by; lz[t+256]=bz;
      ls[t+256] = __fadd_rn(__fadd_rn(__fmul_rn(bx,bx),__fmul_rn(by,by)),__fmul_rn(bz,bz));
    }
    __syncthreads();
#pragma unroll
    for (int q=0;q<8;q++){
      if (cnt[q] >= NSAMP) continue;
      int s = sbase + q;
      int* op = idxo + ((size_t)(b*SPTS + s))*NSAMP;
      for (int c=0;c<8;c++){
        int li = c*64 + lane;
        float dot = fmaf(nz[q], lz[li], fmaf(ny[q], ly[li], __fmul_rn(nx[q], lx[li])));
        float sq  = __fsub_rn(__fadd_rn(sn[q], ls[li]), __fmul_rn(2.0f, dot));
        bool in = (sq <= rsq);
        unsigned long long m = __ballot(in);
        if (cnt[q]==0 && m) first[q] = T*512 + c*64 + (int)__builtin_ctzll(m);
        if (in){
          int slot = cnt[q] + (int)__popcll(m & ((1ull<<lane)-1ull));
          if (slot < NSAMP) op[slot] = T*512 + li;
        }
        cnt[q] += (int)__popcll(m);
        if (cnt[q] >= NSAMP){ if (lane==0) atomicAdd(&done,1); break; }
      }
    }
    __syncthreads();
    if (done >= 32) break;   // uniform across the block
  }
#pragma unroll
  for (int q=0;q<8;q++){
    if (cnt[q] < NSAMP){
      int s = sbase + q;
      int* op = idxo + ((size_t)(b*SPTS + s))*NSAMP;
      if (lane >= cnt[q] && lane < NSAMP) op[lane] = first[q];
    }
  }
}

// ---------------- GEMM1: gather x w1 -> y1 (bf16) + bucketed fused stats ----------------
__global__ __launch_bounds__(256) void gemm1_kernel(const float* __restrict__ xyz,
                                                    const float* __restrict__ ptsT,
                                                    const int* __restrict__ idx,
                                                    const float* __restrict__ newxyz,
                                                    const float* __restrict__ w1,
                                                    const float* __restrict__ b1,
                                                    uint16_t* __restrict__ y1,
                                                    float* __restrict__ gsum,
                                                    float* __restrict__ gsq){
  __shared__ float As[128*69];     // reused as stats scratch in epilogue
  __shared__ float Ws[67*64];
  __shared__ float bias[64];
  __shared__ int   ndx[128];
  __shared__ float nxs[4][3];
  int t = threadIdx.x;
  int g0 = blockIdx.x*128;
  if (t < 128) ndx[t] = idx[g0 + t];
  if (t < 12){
    int grp = t/3, c = t%3;
    int bs = (g0>>5) + grp; int b = bs>>10, s = bs & 1023;
    nxs[grp][c] = newxyz[(size_t)b*3*SPTS + c*SPTS + s];
  }
  if (t < 64) bias[t] = b1[t];
  for (int e=t; e<67*64; e+=256){ int k=e>>6, c=e&63; Ws[k*64+c] = w1[c*67+k]; }
  __syncthreads();
  {
    int r = t>>1, h = t&1;
    int n = ndx[r];
    int bs = (g0>>5) + (r>>5); int b = bs>>10;
    const float* pr = ptsT + ((size_t)(b*NPTS + n))*64 + h*32;
    float* ar = As + r*69;
    if (h==0){
      int grp = r>>5;
      ar[0] = __fsub_rn(xyz[(size_t)b*3*NPTS + n],          nxs[grp][0]);
      ar[1] = __fsub_rn(xyz[(size_t)b*3*NPTS + NPTS + n],   nxs[grp][1]);
      ar[2] = __fsub_rn(xyz[(size_t)b*3*NPTS + 2*NPTS + n], nxs[grp][2]);
    }
    float* ap = ar + 3 + h*32;
#pragma unroll
    for (int j=0;j<8;j++){
      float4 v = *(const float4*)(pr + j*4);
      ap[j*4+0]=v.x; ap[j*4+1]=v.y; ap[j*4+2]=v.z; ap[j*4+3]=v.w;
    }
  }
  __syncthreads();
  int rg = t>>3, cg = t&7;
  float acc[4][8];
#pragma unroll
  for (int i=0;i<4;i++)
#pragma unroll
    for (int j=0;j<8;j++) acc[i][j]=0.f;
  for (int k=0;k<67;k++){
    float a0 = As[(rg*4+0)*69+k];
    float a1 = As[(rg*4+1)*69+k];
    float a2 = As[(rg*4+2)*69+k];
    float a3 = As[(rg*4+3)*69+k];
    const float* wr = Ws + k*64 + cg*8;
    float4 w0 = *(const float4*)wr;
    float4 w1v = *(const float4*)(wr+4);
    float wj[8] = {w0.x,w0.y,w0.z,w0.w,w1v.x,w1v.y,w1v.z,w1v.w};
#pragma unroll
    for (int j=0;j<8;j++){
      acc[0][j] = fmaf(a0, wj[j], acc[0][j]);
      acc[1][j] = fmaf(a1, wj[j], acc[1][j]);
      acc[2][j] = fmaf(a2, wj[j], acc[2][j]);
      acc[3][j] = fmaf(a3, wj[j], acc[3][j]);
    }
  }
  float ps[8], pq[8];
#pragma unroll
  for (int j=0;j<8;j++){ ps[j]=0.f; pq[j]=0.f; }
#pragma unroll
  for (int i=0;i<4;i++){
    int gr = g0 + rg*4 + i;
    uint16_t* yr = y1 + (size_t)gr*64 + cg*8;
    uint4 vv; uint32_t u[4]; float vj[8];
#pragma unroll
    for (int j=0;j<8;j++){
      vj[j] = acc[i][j] + bias[cg*8+j];
      ps[j] += vj[j]; pq[j] += vj[j]*vj[j];
    }
#pragma unroll
    for (int j=0;j<4;j++)
      u[j] = (uint32_t)f2bf(vj[2*j]) | ((uint32_t)f2bf(vj[2*j+1])<<16);
    vv.x=u[0]; vv.y=u[1]; vv.z=u[2]; vv.w=u[3];
    *(uint4*)yr = vv;
  }
  __syncthreads();                 // all As reads done -> reuse as red[]
  float* red = As;                 // [32][65] sums, +2080 sq
#pragma unroll
  for (int j=0;j<8;j++){
    red[rg*65 + cg*8 + j]        = ps[j];
    red[2080 + rg*65 + cg*8 + j] = pq[j];
  }
  __syncthreads();
  if (t < 64){
    float s=0.f, q=0.f;
    for (int r=0;r<32;r++){ s += red[r*65+t]; q += red[2080 + r*65 + t]; }
    int kb = (blockIdx.x & 15) * 128;
    atomicAdd(&gsum[kb + t], s); atomicAdd(&gsq[kb + t], q);
  }
}

// ---------------- GEMM2: relu(bn(y1)) x w2 -> y2, bucketed finalize-in + stats-out ----------------
__global__ __launch_bounds__(256) void gemm2_kernel(const uint16_t* __restrict__ yin,
                                                    const float* __restrict__ w2,
                                                    const float* __restrict__ b2,
                                                    const float* __restrict__ gsumi,
                                                    const float* __restrict__ gsqi,
                                                    const float* __restrict__ gi,
                                                    const float* __restrict__ bei,
                                                    uint16_t* __restrict__ yout,
                                                    float* __restrict__ gsum,
                                                    float* __restrict__ gsq){
  __shared__ float As[128*65];     // reused as stats scratch in epilogue
  __shared__ float Ws[64*64];
  __shared__ float bias[64], sc[64], sh[64];
  int t = threadIdx.x;
  int g0 = blockIdx.x*128;
  if (t < 64){
    bias[t]=b2[t];
    double ssum=0.0, ssq=0.0;
    for (int k2=0;k2<16;k2++){ ssum += (double)gsumi[k2*128+t]; ssq += (double)gsqi[k2*128+t]; }
    double mean = ssum / (double)MTOT;
    double var  = ssq / (double)MTOT - mean*mean;
    double sv   = (double)gi[t] / sqrt(var + 1e-5);
    sc[t] = (float)sv;
    sh[t] = (float)((double)bei[t] - mean*sv);
  }
  for (int e=t; e<64*64; e+=256){ int k=e>>6, c=e&63; Ws[k*64+c] = w2[c*64+k]; }
  __syncthreads();
  {
    int r = t>>1, h = t&1;
    const uint4* yv = (const uint4*)(yin + (size_t)(g0+r)*64 + h*32);
    float* ar = As + r*65 + h*32;
#pragma unroll
    for (int j=0;j<4;j++){
      uint4 u = yv[j];
      uint32_t vv[4] = {u.x,u.y,u.z,u.w};
#pragma unroll
      for (int m=0;m<4;m++){
        int c = h*32 + j*8 + m*2;
        ar[j*8+m*2]   = fmaxf(fmaf(bfu_lo(vv[m]), sc[c],   sh[c]),   0.f);
        ar[j*8+m*2+1] = fmaxf(fmaf(bfu_hi(vv[m]), sc[c+1], sh[c+1]), 0.f);
      }
    }
  }
  __syncthreads();
  int rg = t>>3, cg = t&7;
  float acc[4][8];
#pragma unroll
  for (int i=0;i<4;i++)
#pragma unroll
    for (int j=0;j<8;j++) acc[i][j]=0.f;
  for (int k=0;k<64;k++){
    float a0 = As[(rg*4+0)*65+k];
    float a1 = As[(rg*4+1)*65+k];
    float a2 = As[(rg*4+2)*65+k];
    float a3 = As[(rg*4+3)*65+k];
    const float* wr = Ws + k*64 + cg*8;
    float4 w0 = *(const float4*)wr;
    float4 w1v = *(const float4*)(wr+4);
    float wj[8] = {w0.x,w0.y,w0.z,w0.w,w1v.x,w1v.y,w1v.z,w1v.w};
#pragma unroll
    for (int j=0;j<8;j++){
      acc[0][j] = fmaf(a0, wj[j], acc[0][j]);
      acc[1][j] = fmaf(a1, wj[j], acc[1][j]);
      acc[2][j] = fmaf(a2, wj[j], acc[2][j]);
      acc[3][j] = fmaf(a3, wj[j], acc[3][j]);
    }
  }
  float ps[8], pq[8];
#pragma unroll
  for (int j=0;j<8;j++){ ps[j]=0.f; pq[j]=0.f; }
#pragma unroll
  for (int i=0;i<4;i++){
    int gr = g0 + rg*4 + i;
    uint16_t* yr = yout + (size_t)gr*64 + cg*8;
    uint4 vv; uint32_t u[4]; float vj[8];
#pragma unroll
    for (int j=0;j<8;j++){
      vj[j] = acc[i][j] + bias[cg*8+j];
      ps[j] += vj[j]; pq[j] += vj[j]*vj[j];
    }
#pragma unroll
    for (int j=0;j<4;j++)
      u[j] = (uint32_t)f2bf(vj[2*j]) | ((uint32_t)f2bf(vj[2*j+1])<<16);
    vv.x=u[0]; vv.y=u[1]; vv.z=u[2]; vv.w=u[3];
    *(uint4*)yr = vv;
  }
  __syncthreads();
  float* red = As;
#pragma unroll
  for (int j=0;j<8;j++){
    red[rg*65 + cg*8 + j]        = ps[j];
    red[2080 + rg*65 + cg*8 + j] = pq[j];
  }
  __syncthreads();
  if (t < 64){
    float s=0.f, q=0.f;
    for (int r=0;r<32;r++){ s += red[r*65+t]; q += red[2080 + r*65 + t]; }
    int kb = (blockIdx.x & 15) * 128;
    atomicAdd(&gsum[kb + t], s); atomicAdd(&gsq[kb + t], q);
  }
}

// ---------------- GEMM3: relu(bn(y2)) x w3 -> y3, bucketed finalize-in + stats-out ----------------
__global__ __launch_bounds__(256) void gemm3_kernel(const uint16_t* __restrict__ yin,
                                                    const float* __restrict__ w3,
                                                    const float* __restrict__ b3,
                                                    const float* __restrict__ gsumi,
                                                    const float* __restrict__ gsqi,
                                                    const float* __restrict__ gi,
                                                    const float* __restrict__ bei,
                                                    uint16_t* __restrict__ yout,
                                                    float* __restrict__ gsum,
                                                    float* __restrict__ gsq){
  __shared__ float As[64*65];      // reused as stats scratch (2*16*129=4128 <= 4160)
  __shared__ float Ws[64*128];
  __shared__ float bias[128], sc[64], sh[64];
  int t = threadIdx.x;
  int g0 = blockIdx.x*64;
  if (t < 128) bias[t]=b3[t];
  if (t < 64){
    double ssum=0.0, ssq=0.0;
    for (int k2=0;k2<16;k2++){ ssum += (double)gsumi[k2*128+t]; ssq += (double)gsqi[k2*128+t]; }
    double mean = ssum / (double)MTOT;
    double var  = ssq / (double)MTOT - mean*mean;
    double sv   = (double)gi[t] / sqrt(var + 1e-5);
    sc[t] = (float)sv;
    sh[t] = (float)((double)bei[t] - mean*sv);
  }
  for (int e=t; e<64*128; e+=256){ int k=e>>7, c=e&127; Ws[k*128+c] = w3[c*64+k]; }
  __syncthreads();
  {
    int r = t>>2, h = t&3;
    const uint4* yv = (const uint4*)(yin + (size_t)(g0+r)*64 + h*16);
    float* ar = As + r*65 + h*16;
#pragma unroll
    for (int j=0;j<2;j++){
      uint4 u = yv[j];
      uint32_t vv[4] = {u.x,u.y,u.z,u.w};
#pragma unroll
      for (int m=0;m<4;m++){
        int c = h*16 + j*8 + m*2;
        ar[j*8+m*2]   = fmaxf(fmaf(bfu_lo(vv[m]), sc[c],   sh[c]),   0.f);
        ar[j*8+m*2+1] = fmaxf(fmaf(bfu_hi(vv[m]), sc[c+1], sh[c+1]), 0.f);
      }
    }
  }
  __syncthreads();
  int rg = t>>4, cg = t&15;
  float acc[4][8];
#pragma unroll
  for (int i=0;i<4;i++)
#pragma unroll
    for (int j=0;j<8;j++) acc[i][j]=0.f;
  for (int k=0;k<64;k++){
    float a0 = As[(rg*4+0)*65+k];
    float a1 = As[(rg*4+1)*65+k];
    float a2 = As[(rg*4+2)*65+k];
    float a3 = As[(rg*4+3)*65+k];
    const float* wr = Ws + k*128 + cg*8;
    float4 w0 = *(const float4*)wr;
    float4 w1v = *(const float4*)(wr+4);
    float wj[8] = {w0.x,w0.y,w0.z,w0.w,w1v.x,w1v.y,w1v.z,w1v.w};
#pragma unroll
    for (int j=0;j<8;j++){
      acc[0][j] = fmaf(a0, wj[j], acc[0][j]);
      acc[1][j] = fmaf(a1, wj[j], acc[1][j]);
      acc[2][j] = fmaf(a2, wj[j], acc[2][j]);
      acc[3][j] = fmaf(a3, wj[j], acc[3][j]);
    }
  }
  float ps[8], pq[8];
#pragma unroll
  for (int j=0;j<8;j++){ ps[j]=0.f; pq[j]=0.f; }
#pragma unroll
  for (int i=0;i<4;i++){
    int gr = g0 + rg*4 + i;
    uint16_t* yr = yout + (size_t)gr*128 + cg*8;
    uint4 vv; uint32_t u[4]; float vj[8];
#pragma unroll
    for (int j=0;j<8;j++){
      vj[j] = acc[i][j] + bias[cg*8+j];
      ps[j] += vj[j]; pq[j] += vj[j]*vj[j];
    }
#pragma unroll
    for (int j=0;j<4;j++)
      u[j] = (uint32_t)f2bf(vj[2*j]) | ((uint32_t)f2bf(vj[2*j+1])<<16);
    vv.x=u[0]; vv.y=u[1]; vv.z=u[2]; vv.w=u[3];
    *(uint4*)yr = vv;
  }
  __syncthreads();
  float* red = As;                 // [16][129] sums, +2064 sq
#pragma unroll
  for (int j=0;j<8;j++){
    red[rg*129 + cg*8 + j]        = ps[j];
    red[2064 + rg*129 + cg*8 + j] = pq[j];
  }
  __syncthreads();
  if (t < 128){
    float s=0.f, q=0.f;
    for (int r=0;r<16;r++){ s += red[r*129+t]; q += red[2064 + r*129 + t]; }
    int kb = (blockIdx.x & 15) * 128;
    atomicAdd(&gsum[kb + t], s); atomicAdd(&gsq[kb + t], q);
  }
}

// ---------------- bn3(bucketed finalize) + relu + maxpool + transpose ----------------
__global__ __launch_bounds__(256) void maxpool_kernel(const uint16_t* __restrict__ y3,
                                                      const float* __restrict__ gsumi,
                                                      const float* __restrict__ gsqi,
                                                      const float* __restrict__ gi,
                                                      const float* __restrict__ bei,
                                                      float* __restrict__ out1){
  __shared__ float tr[16][129];
  __shared__ float scs[128], shs[128];
  int t = threadIdx.x;
  int b = blockIdx.x >> 6;
  int s0 = (blockIdx.x & 63) * 16;
  if (t < 128){
    double ssum=0.0, ssq=0.0;
    for (int k2=0;k2<16;k2++){ ssum += (double)gsumi[k2*128+t]; ssq += (double)gsqi[k2*128+t]; }
    double mean = ssum / (double)MTOT;
    double var  = ssq / (double)MTOT - mean*mean;
    double sv   = (double)gi[t] / sqrt(var + 1e-5);
    scs[t] = (float)sv;
    shs[t] = (float)((double)bei[t] - mean*sv);
  }
  __syncthreads();
  int ch = t & 127, sl0 = t >> 7;
  float scv = scs[ch], shv = shs[ch];
  for (int sl=sl0; sl<16; sl+=2){
    int bs = b*SPTS + s0 + sl;
    const uint16_t* yr = y3 + (size_t)bs*NSAMP*128 + ch;
    float m = 0.0f;
#pragma unroll 4
    for (int k=0;k<NSAMP;k++){
      float v = __uint_as_float(((uint32_t)yr[k*128])<<16);
      float z = fmaxf(fmaf(v, scv, shv), 0.f);
      m = fmaxf(m, z);
    }
    tr[sl][ch] = m;
  }
  __syncthreads();
  int ch2 = t >> 1, hh = t & 1;
  float vals[8];
#pragma unroll
  for (int i=0;i<8;i++) vals[i] = tr[hh*8+i][ch2];
  float* op = out1 + (size_t)b*131072 + (size_t)ch2*1024 + s0 + hh*8;
  float4 v0; v0.x=vals[0]; v0.y=vals[1]; v0.z=vals[2]; v0.w=vals[3];
  float4 v1; v1.x=vals[4]; v1.y=vals[5]; v1.z=vals[6]; v1.w=vals[7];
  *(float4*)op = v0;
  *(float4*)(op+4) = v1;
}

extern "C" void kernel_launch(void* const* d_in, const int* in_sizes, int n_in,
                              void* d_out, int out_size, void* d_ws, size_t ws_size,
                              hipStream_t stream){
  (void)in_sizes; (void)n_in; (void)out_size; (void)ws_size;
  const float* xyz = (const float*)d_in[0];
  const float* pts = (const float*)d_in[1];
  const float* w1 = (const float*)d_in[2];  const float* b1 = (const float*)d_in[3];
  const float* g1 = (const float*)d_in[4];  const float* be1 = (const float*)d_in[5];
  const float* w2 = (const float*)d_in[6];  const float* b2 = (const float*)d_in[7];
  const float* g2 = (const float*)d_in[8];  const float* be2 = (const float*)d_in[9];
  const float* w3 = (const float*)d_in[10]; const float* b3 = (const float*)d_in[11];
  const float* g3 = (const float*)d_in[12]; const float* be3 = (const float*)d_in[13];

  float* out0 = (float*)d_out;                 // (B,3,1024)
  float* out1 = out0 + BATCH*3*SPTS;           // (B,128,1024)

  char* ws = (char*)d_ws;
  float*    ptsT = (float*)(ws + 0);                       // 33,554,432 B
  float*    stats = (float*)(ws + 33554432);               // 49,152 B (gap before idx)
  int*      idx  = (int*)  (ws + 34078720);                //  1,048,576 B
  uint16_t* y1   = (uint16_t*)(ws + 35127296);             // 33,554,432 B
  uint16_t* y2   = (uint16_t*)(ws + 68681728);             // 33,554,432 B
  uint16_t* y3   = (uint16_t*)(ws + 102236160);            // 67,108,864 B
  // layer L: gsum buckets = stats + L*4096, gsq buckets = +2048 (16 buckets x 128 ch)
  float* gsum1 = stats;          float* gsq1 = stats + 2048;
  float* gsum2 = stats + 4096;   float* gsq2 = stats + 6144;
  float* gsum3 = stats + 8192;   float* gsq3 = stats + 10240;

  hipMemsetAsync(stats, 0, 12288*sizeof(float), stream);

  fps_kernel<<<BATCH + 2048, 512, 0, stream>>>(xyz, out0, pts, ptsT);
  ball_kernel<<<BATCH*32, 256, 0, stream>>>(xyz, out0, idx);
  gemm1_kernel<<<MTOT/128, 256, 0, stream>>>(xyz, ptsT, idx, out0, w1, b1, y1, gsum1, gsq1);
  gemm2_kernel<<<MTOT/128, 256, 0, stream>>>(y1, w2, b2, gsum1, gsq1, g1, be1, y2, gsum2, gsq2);
  gemm3_kernel<<<MTOT/64, 256, 0, stream>>>(y2, w3, b3, gsum2, gsq2, g2, be2, y3, gsum3, gsq3);
  maxpool_kernel<<<BATCH*(SPTS/16), 256, 0, stream>>>(y3, gsum3, gsq3, g3, be3, out1);
}

// Round 15
// 2610.646 us; speedup vs baseline: 3.9737x; 1.0024x over previous
//
#include <hip/hip_runtime.h>
#include <hip/hip_bf16.h>
#include <stdint.h>

#define BATCH 8
#define NPTS  16384
#define DIMF  64
#define SPTS  1024
#define NSAMP 32
#define MTOT  (BATCH*SPTS*NSAMP)   // 262144

__device__ __forceinline__ float bfu_lo(uint32_t u){ return __uint_as_float(u<<16); }
__device__ __forceinline__ float bfu_hi(uint32_t u){ return __uint_as_float(u & 0xffff0000u); }
__device__ __forceinline__ uint16_t f2bf(float f){
  __hip_bfloat16 h = __float2bfloat16(f);
  uint16_t u; __builtin_memcpy(&u, &h, 2); return u;
}

// ---------------- FPS (R5 variant) + transpose folded in ----------------
__global__ __launch_bounds__(512, 2) void fps_kernel(const float* __restrict__ xyz,
                                                     float* __restrict__ out0,
                                                     const float* __restrict__ pts,
                                                     float* __restrict__ ptsT){
  if (blockIdx.x >= BATCH){
    __shared__ float tile[64][65];
    int bb = blockIdx.x - BATCH;       // 0..2047
    int b  = bb >> 8;                  // 256 slabs per batch
    int n0 = (bb & 255) << 6;
    const float* src = pts + (size_t)b*DIMF*NPTS;
    float* dst = ptsT + (size_t)b*NPTS*DIMF;
    int t = threadIdx.x;
    int cn = t & 63, cw = t >> 6;      // 8 groups of 64 lanes
#pragma unroll
    for (int j=0;j<8;j++){
      int c = cw + j*8;
      tile[c][cn] = src[(size_t)c*NPTS + n0 + cn];
    }
    __syncthreads();
#pragma unroll
    for (int j=0;j<8;j++){
      int nl = cw + j*8;
      dst[(size_t)(n0+nl)*DIMF + cn] = tile[cn][nl];
    }
    return;
  }
  int b = blockIdx.x;
  const float* X = xyz + (size_t)b*3*NPTS;
  int t = threadIdx.x;
  int lane = t & 63, wid = t >> 6;   // 8 waves
  float px[32], py[32], pz[32], dst[32];
#pragma unroll
  for (int k=0;k<32;k++){
    int n = t + (k<<9);
    px[k]=X[n]; py[k]=X[NPTS+n]; pz[k]=X[2*NPTS+n];
    dst[k]=1e10f;
  }
  __shared__ float rv[2][8];
  __shared__ int   ri[2][8];
  int far = 0;
  float* o = out0 + (size_t)b*3*SPTS;
  for (int s=0;s<SPTS;s++){
    float cx = X[far], cy = X[NPTS+far], cz = X[2*NPTS+far];
    if (t==0){ o[s]=cx; o[SPTS+s]=cy; o[2*SPTS+s]=cz; }
    if (s==SPTS-1) break;
    float best = -1.0f; int bi = 0x7fffffff;
#pragma unroll
    for (int k=0;k<32;k++){
      float dx=__fsub_rn(px[k],cx), dy=__fsub_rn(py[k],cy), dz=__fsub_rn(pz[k],cz);
      float d = __fadd_rn(__fadd_rn(__fmul_rn(dx,dx),__fmul_rn(dy,dy)),__fmul_rn(dz,dz));
      d = fminf(dst[k], d); dst[k] = d;
      if (d > best){ best = d; bi = t + (k<<9); }   // ascending n in k -> first-max
    }
#pragma unroll
    for (int off=1; off<64; off<<=1){
      float ov = __shfl_xor(best, off);
      int   oi = __shfl_xor(bi, off);
      if (ov > best || (ov == best && oi < bi)){ best = ov; bi = oi; }
    }
    int p = s & 1;
    if (lane==0){ rv[p][wid]=best; ri[p][wid]=bi; }
    __syncthreads();
    float v = rv[p][lane&7]; int j = ri[p][lane&7];
#pragma unroll
    for (int off=1; off<8; off<<=1){
      float ov = __shfl_xor(v, off);
      int   oj = __shfl_xor(j, off);
      if (ov > v || (ov == v && oj < j)){ v = ov; j = oj; }
    }
    far = j;   // identical in every lane/wave
  }
}

// ---------------- ball query: XLA-CPU f32 replication ----------------
__global__ __launch_bounds__(256) void ball_kernel(const float* __restrict__ xyz,
                                                   const float* __restrict__ newxyz,
                                                   int* __restrict__ idxo){
  int b  = blockIdx.x >> 5;
  int sc = blockIdx.x & 31;           // 32 s per block
  const float* X  = xyz + (size_t)b*3*NPTS;
  int t = threadIdx.x, lane = t & 63, w = t >> 6;
  __shared__ float lx[512], ly[512], lz[512], ls[512];
  __shared__ int done;
  if (t==0) done = 0;
  const float rsq = 0.01f;
  float nx[8], ny[8], nz[8], sn[8];
  int cnt[8], first[8];
  int sbase = sc*32 + w*8;
#pragma unroll
  for (int q=0;q<8;q++){
    int s = sbase + q;
    nx[q] = newxyz[(size_t)b*3*SPTS + s];
    ny[q] = newxyz[(size_t)b*3*SPTS + SPTS + s];
    nz[q] = newxyz[(size_t)b*3*SPTS + 2*SPTS + s];
    sn[q] = __fadd_rn(__fadd_rn(__fmul_rn(nx[q],nx[q]),__fmul_rn(ny[q],ny[q])),
                      __fmul_rn(nz[q],nz[q]));
    cnt[q]=0; first[q]=0;
  }
  __syncthreads();
  for (int T=0;T<32;T++){
    {
      float ax = X[T*512 + t], ay = X[NPTS + T*512 + t], az = X[2*NPTS + T*512 + t];
      lx[t]=ax; ly[t]=ay; lz[t]=az;
      ls[t] = __fadd_rn(__fadd_rn(__fmul_rn(ax,ax),__fmul_rn(ay,ay)),__fmul_rn(az,az));
      float bx = X[T*512 + t + 256], by = X[NPTS + T*512 + t + 256], bz = X[2*NPTS + T*512 + t + 256];
      lx[t+256]=bx; ly[t+256]=by; lz[t+256]=bz;
      ls[t+256] = __fadd_rn(__fadd_rn(__fmul_rn(bx,bx),__fmul_rn(by,by)),__fmul_rn(bz,bz));
    }
    __syncthreads();
#pragma unroll
    for (int q=0;q<8;q++){
      if (cnt[q] >= NSAMP) continue;
      int s = sbase + q;
      int* op = idxo + ((size_t)(b*SPTS + s))*NSAMP;
      for (int c=0;c<8;c++){
        int li = c*64 + lane;
        float dot = fmaf(nz[q], lz[li], fmaf(ny[q], ly[li], __fmul_rn(nx[q], lx[li])));
        float sq  = __fsub_rn(__fadd_rn(sn[q], ls[li]), __fmul_rn(2.0f, dot));
        bool in = (sq <= rsq);
        unsigned long long m = __ballot(in);
        if (cnt[q]==0 && m) first[q] = T*512 + c*64 + (int)__builtin_ctzll(m);
        if (in){
          int slot = cnt[q] + (int)__popcll(m & ((1ull<<lane)-1ull));
          if (slot < NSAMP) op[slot] = T*512 + li;
        }
        cnt[q] += (int)__popcll(m);
        if (cnt[q] >= NSAMP){ if (lane==0) atomicAdd(&done,1); break; }
      }
    }
    __syncthreads();
    if (done >= 32) break;   // uniform across the block
  }
#pragma unroll
  for (int q=0;q<8;q++){
    if (cnt[q] < NSAMP){
      int s = sbase + q;
      int* op = idxo + ((size_t)(b*SPTS + s))*NSAMP;
      if (lane >= cnt[q] && lane < NSAMP) op[lane] = first[q];
    }
  }
}

// ---------------- GEMM1: gather x w1 -> y1 (bf16) + bucketed fused stats ----------------
__global__ __launch_bounds__(256) void gemm1_kernel(const float* __restrict__ xyz,
                                                    const float* __restrict__ ptsT,
                                                    const int* __restrict__ idx,
                                                    const float* __restrict__ newxyz,
                                                    const float* __restrict__ w1,
                                                    const float* __restrict__ b1,
                                                    uint16_t* __restrict__ y1,
                                                    float* __restrict__ gsum,
                                                    float* __restrict__ gsq){
  __shared__ float As[128*69];     // reused as stats scratch in epilogue
  __shared__ float Ws[67*64];
  __shared__ float bias[64];
  __shared__ int   ndx[128];
  __shared__ float nxs[4][3];
  int t = threadIdx.x;
  int g0 = blockIdx.x*128;
  if (t < 128) ndx[t] = idx[g0 + t];
  if (t < 12){
    int grp = t/3, c = t%3;
    int bs = (g0>>5) + grp; int b = bs>>10, s = bs & 1023;
    nxs[grp][c] = newxyz[(size_t)b*3*SPTS + c*SPTS + s];
  }
  if (t < 64) bias[t] = b1[t];
  for (int e=t; e<67*64; e+=256){ int k=e>>6, c=e&63; Ws[k*64+c] = w1[c*67+k]; }
  __syncthreads();
  {
    int r = t>>1, h = t&1;
    int n = ndx[r];
    int bs = (g0>>5) + (r>>5); int b = bs>>10;
    const float* pr = ptsT + ((size_t)(b*NPTS + n))*64 + h*32;
    float* ar = As + r*69;
    if (h==0){
      int grp = r>>5;
      ar[0] = __fsub_rn(xyz[(size_t)b*3*NPTS + n],          nxs[grp][0]);
      ar[1] = __fsub_rn(xyz[(size_t)b*3*NPTS + NPTS + n],   nxs[grp][1]);
      ar[2] = __fsub_rn(xyz[(size_t)b*3*NPTS + 2*NPTS + n], nxs[grp][2]);
    }
    float* ap = ar + 3 + h*32;
#pragma unroll
    for (int j=0;j<8;j++){
      float4 v = *(const float4*)(pr + j*4);
      ap[j*4+0]=v.x; ap[j*4+1]=v.y; ap[j*4+2]=v.z; ap[j*4+3]=v.w;
    }
  }
  __syncthreads();
  int rg = t>>3, cg = t&7;
  float acc[4][8];
#pragma unroll
  for (int i=0;i<4;i++)
#pragma unroll
    for (int j=0;j<8;j++) acc[i][j]=0.f;
  for (int k=0;k<67;k++){
    float a0 = As[(rg*4+0)*69+k];
    float a1 = As[(rg*4+1)*69+k];
    float a2 = As[(rg*4+2)*69+k];
    float a3 = As[(rg*4+3)*69+k];
    const float* wr = Ws + k*64 + cg*8;
    float4 w0 = *(const float4*)wr;
    float4 w1v = *(const float4*)(wr+4);
    float wj[8] = {w0.x,w0.y,w0.z,w0.w,w1v.x,w1v.y,w1v.z,w1v.w};
#pragma unroll
    for (int j=0;j<8;j++){
      acc[0][j] = fmaf(a0, wj[j], acc[0][j]);
      acc[1][j] = fmaf(a1, wj[j], acc[1][j]);
      acc[2][j] = fmaf(a2, wj[j], acc[2][j]);
      acc[3][j] = fmaf(a3, wj[j], acc[3][j]);
    }
  }
  float ps[8], pq[8];
#pragma unroll
  for (int j=0;j<8;j++){ ps[j]=0.f; pq[j]=0.f; }
#pragma unroll
  for (int i=0;i<4;i++){
    int gr = g0 + rg*4 + i;
    uint16_t* yr = y1 + (size_t)gr*64 + cg*8;
    uint4 vv; uint32_t u[4]; float vj[8];
#pragma unroll
    for (int j=0;j<8;j++){
      vj[j] = acc[i][j] + bias[cg*8+j];
      ps[j] += vj[j]; pq[j] += vj[j]*vj[j];
    }
#pragma unroll
    for (int j=0;j<4;j++)
      u[j] = (uint32_t)f2bf(vj[2*j]) | ((uint32_t)f2bf(vj[2*j+1])<<16);
    vv.x=u[0]; vv.y=u[1]; vv.z=u[2]; vv.w=u[3];
    *(uint4*)yr = vv;
  }
  __syncthreads();                 // all As reads done -> reuse as red[]
  float* red = As;                 // [32][65] sums, +2080 sq
#pragma unroll
  for (int j=0;j<8;j++){
    red[rg*65 + cg*8 + j]        = ps[j];
    red[2080 + rg*65 + cg*8 + j] = pq[j];
  }
  __syncthreads();
  if (t < 64){
    float s=0.f, q=0.f;
    for (int r=0;r<32;r++){ s += red[r*65+t]; q += red[2080 + r*65 + t]; }
    int kb = (blockIdx.x & 15) * 128;
    atomicAdd(&gsum[kb + t], s); atomicAdd(&gsq[kb + t], q);
  }
}

// ---------------- GEMM2: relu(bn(y1)) x w2 -> y2, bucketed finalize-in + stats-out ----------------
__global__ __launch_bounds__(256) void gemm2_kernel(const uint16_t* __restrict__ yin,
                                                    const float* __restrict__ w2,
                                                    const float* __restrict__ b2,
                                                    const float* __restrict__ gsumi,
                                                    const float* __restrict__ gsqi,
                                                    const float* __restrict__ gi,
                                                    const float* __restrict__ bei,
                                                    uint16_t* __restrict__ yout,
                                                    float* __restrict__ gsum,
                                                    float* __restrict__ gsq){
  __shared__ float As[128*65];     // reused as stats scratch in epilogue
  __shared__ float Ws[64*64];
  __shared__ float bias[64], sc[64], sh[64];
  int t = threadIdx.x;
  int g0 = blockIdx.x*128;
  if (t < 64){
    bias[t]=b2[t];
    double ssum=0.0, ssq=0.0;
    for (int k2=0;k2<16;k2++){ ssum += (double)gsumi[k2*128+t]; ssq += (double)gsqi[k2*128+t]; }
    double mean = ssum / (double)MTOT;
    double var  = ssq / (double)MTOT - mean*mean;
    double sv   = (double)gi[t] / sqrt(var + 1e-5);
    sc[t] = (float)sv;
    sh[t] = (float)((double)bei[t] - mean*sv);
  }
  for (int e=t; e<64*64; e+=256){ int k=e>>6, c=e&63; Ws[k*64+c] = w2[c*64+k]; }
  __syncthreads();
  {
    int r = t>>1, h = t&1;
    const uint4* yv = (const uint4*)(yin + (size_t)(g0+r)*64 + h*32);
    float* ar = As + r*65 + h*32;
#pragma unroll
    for (int j=0;j<4;j++){
      uint4 u = yv[j];
      uint32_t vv[4] = {u.x,u.y,u.z,u.w};
#pragma unroll
      for (int m=0;m<4;m++){
        int c = h*32 + j*8 + m*2;
        ar[j*8+m*2]   = fmaxf(fmaf(bfu_lo(vv[m]), sc[c],   sh[c]),   0.f);
        ar[j*8+m*2+1] = fmaxf(fmaf(bfu_hi(vv[m]), sc[c+1], sh[c+1]), 0.f);
      }
    }
  }
  __syncthreads();
  int rg = t>>3, cg = t&7;
  float acc[4][8];
#pragma unroll
  for (int i=0;i<4;i++)
#pragma unroll
    for (int j=0;j<8;j++) acc[i][j]=0.f;
  for (int k=0;k<64;k++){
    float a0 = As[(rg*4+0)*65+k];
    float a1 = As[(rg*4+1)*65+k];
    float a2 = As[(rg*4+2)*65+k];
    float a3 = As[(rg*4+3)*65+k];
    const float* wr = Ws + k*64 + cg*8;
    float4 w0 = *(const float4*)wr;
    float4 w1v = *(const float4*)(wr+4);
    float wj[8] = {w0.x,w0.y,w0.z,w0.w,w1v.x,w1v.y,w1v.z,w1v.w};
#pragma unroll
    for (int j=0;j<8;j++){
      acc[0][j] = fmaf(a0, wj[j], acc[0][j]);
      acc[1][j] = fmaf(a1, wj[j], acc[1][j]);
      acc[2][j] = fmaf(a2, wj[j], acc[2][j]);
      acc[3][j] = fmaf(a3, wj[j], acc[3][j]);
    }
  }
  float ps[8], pq[8];
#pragma unroll
  for (int j=0;j<8;j++){ ps[j]=0.f; pq[j]=0.f; }
#pragma unroll
  for (int i=0;i<4;i++){
    int gr = g0 + rg*4 + i;
    uint16_t* yr = yout + (size_t)gr*64 + cg*8;
    uint4 vv; uint32_t u[4]; float vj[8];
#pragma unroll
    for (int j=0;j<8;j++){
      vj[j] = acc[i][j] + bias[cg*8+j];
      ps[j] += vj[j]; pq[j] += vj[j]*vj[j];
    }
#pragma unroll
    for (int j=0;j<4;j++)
      u[j] = (uint32_t)f2bf(vj[2*j]) | ((uint32_t)f2bf(vj[2*j+1])<<16);
    vv.x=u[0]; vv.y=u[1]; vv.z=u[2]; vv.w=u[3];
    *(uint4*)yr = vv;
  }
  __syncthreads();
  float* red = As;
#pragma unroll
  for (int j=0;j<8;j++){
    red[rg*65 + cg*8 + j]        = ps[j];
    red[2080 + rg*65 + cg*8 + j] = pq[j];
  }
  __syncthreads();
  if (t < 64){
    float s=0.f, q=0.f;
    for (int r=0;r<32;r++){ s += red[r*65+t]; q += red[2080 + r*65 + t]; }
    int kb = (blockIdx.x & 15) * 128;
    atomicAdd(&gsum[kb + t], s); atomicAdd(&gsq[kb + t], q);
  }
}

// ---------------- GEMM3: relu(bn(y2)) x w3 -> per-(s,ch) M/m + stats (y3 eliminated) ----------------
// max_k relu(fmaf(v,sc,sh)) == relu(fmaf(M,sc,sh)) for sc>=0, relu(fmaf(m,sc,sh)) for sc<0
// (fmaf/relu monotone in v), so only per-group max M and min m of pre-BN values are needed.
__global__ __launch_bounds__(256) void gemm3_kernel(const uint16_t* __restrict__ yin,
                                                    const float* __restrict__ w3,
                                                    const float* __restrict__ b3,
                                                    const float* __restrict__ gsumi,
                                                    const float* __restrict__ gsqi,
                                                    const float* __restrict__ gi,
                                                    const float* __restrict__ bei,
                                                    float* __restrict__ Mb,
                                                    float* __restrict__ mb,
                                                    float* __restrict__ gsum,
                                                    float* __restrict__ gsq){
  __shared__ float As[64*65];      // reused: stats scratch, then M/m scratch
  __shared__ float Ws[64*128];
  __shared__ float bias[128], sc[64], sh[64];
  int t = threadIdx.x;
  int g0 = blockIdx.x*64;
  if (t < 128) bias[t]=b3[t];
  if (t < 64){
    double ssum=0.0, ssq=0.0;
    for (int k2=0;k2<16;k2++){ ssum += (double)gsumi[k2*128+t]; ssq += (double)gsqi[k2*128+t]; }
    double mean = ssum / (double)MTOT;
    double var  = ssq / (double)MTOT - mean*mean;
    double sv   = (double)gi[t] / sqrt(var + 1e-5);
    sc[t] = (float)sv;
    sh[t] = (float)((double)bei[t] - mean*sv);
  }
  for (int e=t; e<64*128; e+=256){ int k=e>>7, c=e&127; Ws[k*128+c] = w3[c*64+k]; }
  __syncthreads();
  {
    int r = t>>2, h = t&3;
    const uint4* yv = (const uint4*)(yin + (size_t)(g0+r)*64 + h*16);
    float* ar = As + r*65 + h*16;
#pragma unroll
    for (int j=0;j<2;j++){
      uint4 u = yv[j];
      uint32_t vv[4] = {u.x,u.y,u.z,u.w};
#pragma unroll
      for (int m=0;m<4;m++){
        int c = h*16 + j*8 + m*2;
        ar[j*8+m*2]   = fmaxf(fmaf(bfu_lo(vv[m]), sc[c],   sh[c]),   0.f);
        ar[j*8+m*2+1] = fmaxf(fmaf(bfu_hi(vv[m]), sc[c+1], sh[c+1]), 0.f);
      }
    }
  }
  __syncthreads();
  int rg = t>>4, cg = t&15;
  float acc[4][8];
#pragma unroll
  for (int i=0;i<4;i++)
#pragma unroll
    for (int j=0;j<8;j++) acc[i][j]=0.f;
  for (int k=0;k<64;k++){
    float a0 = As[(rg*4+0)*65+k];
    float a1 = As[(rg*4+1)*65+k];
    float a2 = As[(rg*4+2)*65+k];
    float a3 = As[(rg*4+3)*65+k];
    const float* wr = Ws + k*128 + cg*8;
    float4 w0 = *(const float4*)wr;
    float4 w1v = *(const float4*)(wr+4);
    float wj[8] = {w0.x,w0.y,w0.z,w0.w,w1v.x,w1v.y,w1v.z,w1v.w};
#pragma unroll
    for (int j=0;j<8;j++){
      acc[0][j] = fmaf(a0, wj[j], acc[0][j]);
      acc[1][j] = fmaf(a1, wj[j], acc[1][j]);
      acc[2][j] = fmaf(a2, wj[j], acc[2][j]);
      acc[3][j] = fmaf(a3, wj[j], acc[3][j]);
    }
  }
  float ps[8], pq[8], tmax[8], tmin[8];
#pragma unroll
  for (int j=0;j<8;j++){ ps[j]=0.f; pq[j]=0.f; tmax[j]=-1e30f; tmin[j]=1e30f; }
#pragma unroll
  for (int i=0;i<4;i++){
    float vj;
#pragma unroll
    for (int j=0;j<8;j++){
      vj = acc[i][j] + bias[cg*8+j];
      ps[j] += vj; pq[j] += vj*vj;
      tmax[j] = fmaxf(tmax[j], vj); tmin[j] = fminf(tmin[j], vj);
    }
  }
  // stats reduce (As reuse #1)
  __syncthreads();
  float* red = As;                 // [16][129] sums, +2064 sq
#pragma unroll
  for (int j=0;j<8;j++){
    red[rg*129 + cg*8 + j]        = ps[j];
    red[2064 + rg*129 + cg*8 + j] = pq[j];
  }
  __syncthreads();
  if (t < 128){
    float s=0.f, q=0.f;
    for (int r=0;r<16;r++){ s += red[r*129+t]; q += red[2064 + r*129 + t]; }
    int kb = (blockIdx.x & 15) * 128;
    atomicAdd(&gsum[kb + t], s); atomicAdd(&gsq[kb + t], q);
  }
  // M/m reduce (As reuse #2): rows rg*4..rg*4+3 all belong to s-half rg>>3
  __syncthreads();
  float* redM = As;                // [16][129] max, +2064 min
#pragma unroll
  for (int j=0;j<8;j++){
    redM[rg*129 + cg*8 + j]        = tmax[j];
    redM[2064 + rg*129 + cg*8 + j] = tmin[j];
  }
  __syncthreads();
  {
    int h = t >> 7, ch = t & 127;    // 2 halves x 128 channels = 256 threads
    float M=-1e30f, m=1e30f;
    for (int r=h*8; r<h*8+8; r++){
      M = fmaxf(M, redM[r*129+ch]);
      m = fminf(m, redM[2064 + r*129 + ch]);
    }
    int sg = (g0>>5) + h;            // global group index b*1024+s
    Mb[(size_t)sg*128 + ch] = M;
    mb[(size_t)sg*128 + ch] = m;
  }
}

// ---------------- bn3(bucketed finalize) + monotone maxpool from M/m + transpose ----------------
__global__ __launch_bounds__(256) void maxpool_kernel(const float* __restrict__ Mb,
                                                      const float* __restrict__ mb,
                                                      const float* __restrict__ gsumi,
                                                      const float* __restrict__ gsqi,
                                                      const float* __restrict__ gi,
                                                      const float* __restrict__ bei,
                                                      float* __restrict__ out1){
  __shared__ float scs[128], shs[128];
  int t = threadIdx.x;
  int b = blockIdx.x >> 4;
  int s0 = (blockIdx.x & 15) * 64;
  if (t < 128){
    double ssum=0.0, ssq=0.0;
    for (int k2=0;k2<16;k2++){ ssum += (double)gsumi[k2*128+t]; ssq += (double)gsqi[k2*128+t]; }
    double mean = ssum / (double)MTOT;
    double var  = ssq / (double)MTOT - mean*mean;
    double sv   = (double)gi[t] / sqrt(var + 1e-5);
    scs[t] = (float)sv;
    shs[t] = (float)((double)bei[t] - mean*sv);
  }
  __syncthreads();
  int ch = t >> 1, sg2 = t & 1;      // 128 ch x 2 s-subgroups
  float scv = scs[ch], shv = shs[ch];
  bool pos = (scv >= 0.f);
  float buf[32];
#pragma unroll 8
  for (int k=0;k<32;k++){
    int s = s0 + sg2*32 + k;
    size_t g = (size_t)(b*SPTS + s)*128 + ch;
    float v = pos ? Mb[g] : mb[g];
    buf[k] = fmaxf(fmaf(v, scv, shv), 0.f);
  }
  float* op = out1 + (size_t)b*131072 + (size_t)ch*1024 + s0 + sg2*32;
#pragma unroll
  for (int k=0;k<8;k++){
    float4 v4; v4.x=buf[4*k]; v4.y=buf[4*k+1]; v4.z=buf[4*k+2]; v4.w=buf[4*k+3];
    ((float4*)op)[k] = v4;
  }
}

extern "C" void kernel_launch(void* const* d_in, const int* in_sizes, int n_in,
                              void* d_out, int out_size, void* d_ws, size_t ws_size,
                              hipStream_t stream){
  (void)in_sizes; (void)n_in; (void)out_size; (void)ws_size;
  const float* xyz = (const float*)d_in[0];
  const float* pts = (const float*)d_in[1];
  const float* w1 = (const float*)d_in[2];  const float* b1 = (const float*)d_in[3];
  const float* g1 = (const float*)d_in[4];  const float* be1 = (const float*)d_in[5];
  const float* w2 = (const float*)d_in[6];  const float* b2 = (const float*)d_in[7];
  const float* g2 = (const float*)d_in[8];  const float* be2 = (const float*)d_in[9];
  const float* w3 = (const float*)d_in[10]; const float* b3 = (const float*)d_in[11];
  const float* g3 = (const float*)d_in[12]; const float* be3 = (const float*)d_in[13];

  float* out0 = (float*)d_out;                 // (B,3,1024)
  float* out1 = out0 + BATCH*3*SPTS;           // (B,128,1024)

  char* ws = (char*)d_ws;
  float*    ptsT = (float*)(ws + 0);                       // 33,554,432 B
  float*    stats = (float*)(ws + 33554432);               // 49,152 B gap
  int*      idx  = (int*)  (ws + 34078720);                //  1,048,576 B
  uint16_t* y1   = (uint16_t*)(ws + 35127296);             // 33,554,432 B
  uint16_t* y2   = (uint16_t*)(ws + 68681728);             // 33,554,432 B
  float*    Mb   = (float*)(ws + 102236160);               //  4,194,304 B
  float*    mb   = (float*)(ws + 106430464);               //  4,194,304 B
  float* gsum1 = stats;          float* gsq1 = stats + 2048;
  float* gsum2 = stats + 4096;   float* gsq2 = stats + 6144;
  float* gsum3 = stats + 8192;   float* gsq3 = stats + 10240;

  hipMemsetAsync(stats, 0, 12288*sizeof(float), stream);

  fps_kernel<<<BATCH + 2048, 512, 0, stream>>>(xyz, out0, pts, ptsT);
  ball_kernel<<<BATCH*32, 256, 0, stream>>>(xyz, out0, idx);
  gemm1_kernel<<<MTOT/128, 256, 0, stream>>>(xyz, ptsT, idx, out0, w1, b1, y1, gsum1, gsq1);
  gemm2_kernel<<<MTOT/128, 256, 0, stream>>>(y1, w2, b2, gsum1, gsq1, g1, be1, y2, gsum2, gsq2);
  gemm3_kernel<<<MTOT/64, 256, 0, stream>>>(y2, w3, b3, gsum2, gsq2, g2, be2, Mb, mb, gsum3, gsq3);
  maxpool_kernel<<<BATCH*16, 256, 0, stream>>>(Mb, mb, gsum3, gsq3, g3, be3, out1);
}